// Round 4
// baseline (411.166 us; speedup 1.0000x reference)
//
#include <hip/hip_runtime.h>

typedef unsigned short u16;
typedef float  f32x4  __attribute__((ext_vector_type(4)));
typedef unsigned short u16x4 __attribute__((ext_vector_type(4)));
typedef short  bf16x8 __attribute__((ext_vector_type(8)));

__device__ __forceinline__ u16 f2bf(float f) {
  unsigned x = __builtin_bit_cast(unsigned, f);
  x += 0x7fffu + ((x >> 16) & 1u);           // RTN-even
  return (u16)(x >> 16);
}
__device__ __forceinline__ float bf2f(u16 u) {
  return __builtin_bit_cast(float, (unsigned)u << 16);
}

// ---------------- split fp32 -> (hi,lo) bf16 ----------------
__global__ void split_kernel(const float* __restrict__ x, u16* __restrict__ xh,
                             u16* __restrict__ xl, int n4) {
  int i = blockIdx.x * blockDim.x + threadIdx.x;
  int stride = gridDim.x * blockDim.x;
  for (; i < n4; i += stride) {
    f32x4 v = ((const f32x4*)x)[i];
    u16x4 h, l;
#pragma unroll
    for (int j = 0; j < 4; ++j) {
      u16 hh = f2bf(v[j]);
      h[j] = hh;
      l[j] = f2bf(v[j] - bf2f(hh));
    }
    ((u16x4*)xh)[i] = h;
    ((u16x4*)xl)[i] = l;
  }
}

// ---------------- transpose + split (for Wv) ----------------
__global__ void transpose_split_kernel(const float* __restrict__ W,
                                       u16* __restrict__ Th, u16* __restrict__ Tl) {
  int i = blockIdx.x * 256 + threadIdx.x;    // exactly 768*768 threads
  int h = i / 768, d = i % 768;
  float v = W[d * 768 + h];
  u16 hi = f2bf(v);
  Th[i] = hi;
  Tl[i] = f2bf(v - bf2f(hi));
}

// ---------------- GEMM: C = A * B^T ----------------
// 128x128 tile, BK=32, 4 waves (2x2 of 64x64), 16x16x32 bf16 MFMA.
// Double-buffered LDS (stage t+1 before compute t, ONE barrier per K-step).
// Bank swizzle: LDS chunk c of row r holds global k-chunk c ^ ((r>>1)&3).
// XCD-chunk bijective blockIdx remap (m204) for L2 locality.
// EPI: 0 = f32 store (+causal mask), 1 = split bf16 pair, 2 = bf16
// KROW: 0 = full K; 1 = K_eff=(ti+1)*128; 2 = triangle-paired: block does
//       row-tiles p and 15-p sequentially (load-balanced causal PV).
#define GLL16(g, l)                                                              \
  __builtin_amdgcn_global_load_lds(                                              \
      (const __attribute__((address_space(1))) unsigned int*)(g),                \
      (__attribute__((address_space(3))) unsigned int*)(l), 16, 0, 0)

template <int SPLIT, int EPI, int CAUSAL, int KROW>
__global__ __launch_bounds__(256, 2) void gemm_k(
    const u16* __restrict__ Ah, const u16* __restrict__ Al, long sAb,
    const u16* __restrict__ Bh, const u16* __restrict__ Bl, long sBb,
    void* __restrict__ Cv, void* __restrict__ C2v, long sCb,
    int K, int lda, int ldb, int ldc, int gx, int gy) {
  // ---- bijective XCD-chunk remap ----
  const int nwg = gridDim.x;
  const int orig = blockIdx.x;
  const int q8 = nwg >> 3, r8 = nwg & 7;
  const int xcd = orig & 7, pos = orig >> 3;
  const int wgid = (xcd < r8 ? xcd * (q8 + 1) : r8 * (q8 + 1) + (xcd - r8) * q8) + pos;
  const int tj = wgid % gx;
  const int rest = wgid / gx;
  const int ti0 = rest % gy;
  const int zb = rest / gy;
  if (CAUSAL && tj > ti0) return;

  const u16* pAh = Ah + (size_t)zb * sAb;
  const u16* pBh = Bh + (size_t)zb * sBb;
  const u16* pAl = SPLIT ? Al + (size_t)zb * sAb : nullptr;
  const u16* pBl = SPLIT ? Bl + (size_t)zb * sBb : nullptr;

  __shared__ __align__(16) u16 As[2][SPLIT ? 2 : 1][4096];  // [buf][hi/lo][128r x 32k]
  __shared__ __align__(16) u16 Bs[2][SPLIT ? 2 : 1][4096];

  const int t = threadIdx.x, w = t >> 6, l = t & 63;
  const int wr = w >> 1, wc = w & 1;
  const int lr = l & 15, lk = l >> 4;

  // staging: thread t -> LDS row t>>2, chunk t&3; global k-chunk is XOR-swizzled
  const int srow = t >> 2;
  const int sk8 = ((t & 3) ^ ((srow >> 1) & 3)) * 8;
  // swizzled chunk offset for fragment reads (row-bits come only from lr)
  const int ck = ((lk ^ ((lr >> 1) & 3)) << 3);

  const int nhalf = (KROW == 2) ? 2 : 1;
  for (int half = 0; half < nhalf; ++half) {
    const int ti = (KROW == 2) ? (half ? 15 - ti0 : ti0) : ti0;

    const size_t aOff0 = (size_t)(ti * 128 + srow) * lda + sk8;
    const size_t aOff1 = (size_t)(ti * 128 + 64 + srow) * lda + sk8;
    const size_t bOff0 = (size_t)(tj * 128 + srow) * ldb + sk8;
    const size_t bOff1 = (size_t)(tj * 128 + 64 + srow) * ldb + sk8;

    const int Keff = KROW ? (ti + 1) * 128 : K;
    const int nsteps = Keff >> 5;

    auto stage = [&](int bu, int kk) {
      const int kb = kk * 32;
      GLL16(pAh + aOff0 + kb, &As[bu][0][w * 512]);
      GLL16(pAh + aOff1 + kb, &As[bu][0][2048 + w * 512]);
      GLL16(pBh + bOff0 + kb, &Bs[bu][0][w * 512]);
      GLL16(pBh + bOff1 + kb, &Bs[bu][0][2048 + w * 512]);
      if constexpr (SPLIT) {
        GLL16(pAl + aOff0 + kb, &As[bu][1][w * 512]);
        GLL16(pAl + aOff1 + kb, &As[bu][1][2048 + w * 512]);
        GLL16(pBl + bOff0 + kb, &Bs[bu][1][w * 512]);
        GLL16(pBl + bOff1 + kb, &Bs[bu][1][2048 + w * 512]);
      }
    };

    f32x4 acc[4][4] = {};

    stage(0, 0);
    __syncthreads();

    int buf = 0;
    for (int kk = 0; kk < nsteps; ++kk) {
      if (kk + 1 < nsteps) stage(buf ^ 1, kk + 1);  // loads fly during compute

      bf16x8 ah[4], bh[4], al[4], bl[4];
#pragma unroll
      for (int mi = 0; mi < 4; ++mi) {
        const int ae = (wr * 64 + mi * 16 + lr) * 32 + ck;
        const int be = (wc * 64 + mi * 16 + lr) * 32 + ck;
        ah[mi] = *(const bf16x8*)&As[buf][0][ae];
        bh[mi] = *(const bf16x8*)&Bs[buf][0][be];
        if constexpr (SPLIT) {
          al[mi] = *(const bf16x8*)&As[buf][1][ae];
          bl[mi] = *(const bf16x8*)&Bs[buf][1][be];
        }
      }
#pragma unroll
      for (int mi = 0; mi < 4; ++mi)
#pragma unroll
        for (int ni = 0; ni < 4; ++ni) {
          acc[mi][ni] = __builtin_amdgcn_mfma_f32_16x16x32_bf16(ah[mi], bh[ni], acc[mi][ni], 0, 0, 0);
          if constexpr (SPLIT) {
            acc[mi][ni] = __builtin_amdgcn_mfma_f32_16x16x32_bf16(ah[mi], bl[ni], acc[mi][ni], 0, 0, 0);
            acc[mi][ni] = __builtin_amdgcn_mfma_f32_16x16x32_bf16(al[mi], bh[ni], acc[mi][ni], 0, 0, 0);
          }
        }
      __syncthreads();  // drains vmcnt (next tile staged) + all reads of buf done
      buf ^= 1;
    }

    // epilogue: C/D layout col = lane&15, row = (lane>>4)*4 + reg  [m89-verified]
#pragma unroll
    for (int mi = 0; mi < 4; ++mi)
#pragma unroll
      for (int ni = 0; ni < 4; ++ni)
#pragma unroll
        for (int r = 0; r < 4; ++r) {
          const int row = ti * 128 + wr * 64 + mi * 16 + lk * 4 + r;
          const int col = tj * 128 + wc * 64 + ni * 16 + lr;
          float v = acc[mi][ni][r];
          if (CAUSAL && col > row) v = -1e30f;
          const size_t idx = (size_t)zb * sCb + (size_t)row * ldc + col;
          if (EPI == 0) {
            ((float*)Cv)[idx] = v;
          } else if (EPI == 1) {
            u16 hv = f2bf(v);
            ((u16*)Cv)[idx] = hv;
            ((u16*)C2v)[idx] = f2bf(v - bf2f(hv));
          } else {
            ((u16*)Cv)[idx] = f2bf(v);
          }
        }
  }
}

// ---------------- causal row softmax: scores f32 -> P bf16 ----------------
__global__ __launch_bounds__(256) void softmax_kernel(const float* __restrict__ S,
                                                      u16* __restrict__ P,
                                                      long sSb, long sPb) {
  const int wid = blockIdx.x * 4 + (threadIdx.x >> 6);  // one wave per row
  const int l = threadIdx.x & 63;
  const int zb = wid >> 11;
  const int i = wid & 2047;
  const float* row = S + (size_t)zb * sSb + (size_t)i * 2048;
  u16* prow = P + (size_t)zb * sPb + (size_t)i * 2048;
  const int Tend = ((i >> 7) + 1) << 7;  // multiple of 128
  const int nch = (Tend + 255) >> 8;

  f32x4 vb[8];
  float mx = -3e38f;
  for (int c = 0; c < nch; ++c) {
    const int j = c * 256 + l * 4;
    f32x4 v;
    if (j < Tend) v = *(const f32x4*)(row + j);
    else { v[0] = v[1] = v[2] = v[3] = -3e38f; }
    vb[c] = v;
    mx = fmaxf(mx, fmaxf(fmaxf(v[0], v[1]), fmaxf(v[2], v[3])));
  }
#pragma unroll
  for (int s = 32; s; s >>= 1) mx = fmaxf(mx, __shfl_xor(mx, s));

  float sum = 0.f;
  for (int c = 0; c < nch; ++c) {
    f32x4 v = vb[c];
#pragma unroll
    for (int j = 0; j < 4; ++j) {
      float e = expf(v[j] - mx);  // -1e30/-3e38 -> 0
      v[j] = e;
      sum += e;
    }
    vb[c] = v;
  }
#pragma unroll
  for (int s = 32; s; s >>= 1) sum += __shfl_xor(sum, s);
  const float inv = 1.f / sum;

  for (int c = 0; c < nch; ++c) {
    const int j = c * 256 + l * 4;
    if (j < Tend) {
      f32x4 v = vb[c];
      u16x4 o;
#pragma unroll
      for (int q = 0; q < 4; ++q) o[q] = f2bf(v[q] * inv);
      *(u16x4*)(prow + j) = o;
    }
  }
}

// ---------------- orchestration ----------------
extern "C" void kernel_launch(void* const* d_in, const int* in_sizes, int n_in,
                              void* d_out, int out_size, void* d_ws, size_t ws_size,
                              hipStream_t stream) {
  const float* x  = (const float*)d_in[0];
  const float* Wq = (const float*)d_in[1];
  const float* Wk = (const float*)d_in[2];
  const float* Wv = (const float*)d_in[3];
  float* out = (float*)d_out;

  const int S = 2048, D = 768;
  const size_t ND = (size_t)8 * S * D;        // 12.58M
  const size_t NW = (size_t)D * D;            // 589824

  char* ws = (char*)d_ws;
  size_t off = 0;
  auto alloc = [&](size_t bytes) { size_t o = off; off = (off + bytes + 255) & ~(size_t)255; return o; };

  u16* xh  = (u16*)(ws + alloc(ND * 2));
  u16* xl  = (u16*)(ws + alloc(ND * 2));
  u16* qh  = (u16*)(ws + alloc(ND * 2));
  u16* ql  = (u16*)(ws + alloc(ND * 2));
  u16* vt  = (u16*)(ws + alloc(ND * 2));
  u16* wqh = (u16*)(ws + alloc(NW * 2));
  u16* wql = (u16*)(ws + alloc(NW * 2));
  u16* wkh = (u16*)(ws + alloc(NW * 2));
  u16* wkl = (u16*)(ws + alloc(NW * 2));
  u16* wvth = (u16*)(ws + alloc(NW * 2));
  u16* wvtl = (u16*)(ws + alloc(NW * 2));
  u16* mth = (u16*)(ws + alloc(NW * 2));
  u16* mtl = (u16*)(ws + alloc(NW * 2));
  const size_t fixed = off;

  const size_t perBatch = (size_t)S * S * 4 + (size_t)S * S * 2 + 512;  // scores f32 + P bf16
  int g = 0;
  for (int cand = 8; cand >= 1; cand >>= 1)
    if (fixed + (size_t)cand * perBatch <= ws_size) { g = cand; break; }
  if (!g) return;

  float* sc = (float*)(ws + alloc((size_t)g * S * S * 4));
  u16*   P  = (u16*)(ws + alloc((size_t)g * S * S * 2));

  // prep: splits
  split_kernel<<<2048, 256, 0, stream>>>(x, xh, xl, (int)(ND / 4));
  split_kernel<<<576, 256, 0, stream>>>(Wq, wqh, wql, (int)(NW / 4));
  split_kernel<<<576, 256, 0, stream>>>(Wk, wkh, wkl, (int)(NW / 4));
  transpose_split_kernel<<<2304, 256, 0, stream>>>(Wv, wvth, wvtl);

  // Mt[e][d] = sum_h Wk[e][h] * Wq[d][h]   (= (Wq Wk^T)^T), split output
  gemm_k<1, 1, 0, 0><<<36, 256, 0, stream>>>(
      wkh, wkl, 0, wqh, wql, 0, mth, mtl, 0, 768, 768, 768, 768, 6, 6);

  // q'[s][j] = sum_d x[s][d] * Mt[j][d], split output
  gemm_k<1, 1, 0, 0><<<768, 256, 0, stream>>>(
      xh, xl, 0, mth, mtl, 0, qh, ql, 0, 768, 768, 768, 768, 6, 128);

  // vt[h][b*2048+s] = sum_d WvT[h][d] * x[s][d]  (bf16 out)
  gemm_k<0, 2, 0, 0><<<768, 256, 0, stream>>>(
      wvth, nullptr, 0, xh, nullptr, 0, vt, nullptr, 0, 768, 768, 768, 16384, 128, 6);

  for (int b0 = 0; b0 < 8; b0 += g) {
    // scores[b][i][j] = q'[b,i] . x[b,j]  (causal tiles only, mask to -1e30)
    gemm_k<1, 0, 1, 0><<<16 * 16 * g, 256, 0, stream>>>(
        qh + (size_t)b0 * S * D, ql + (size_t)b0 * S * D, (long)S * D,
        xh + (size_t)b0 * S * D, xl + (size_t)b0 * S * D, (long)S * D,
        sc, nullptr, (long)S * S, 768, 768, 768, 2048, 16, 16);

    softmax_kernel<<<g * 512, 256, 0, stream>>>(sc, P, (long)S * S, (long)S * S);

    // out[b][i][h] = sum_{j<Tend} P[b][i][j] * vt[h][b*2048+j]
    // triangle-paired: block handles row-tiles p and 15-p (17 K-steps each)
    gemm_k<0, 0, 0, 2><<<6 * 8 * g, 256, 0, stream>>>(
        P, nullptr, (long)S * S,
        vt + (size_t)b0 * S, nullptr, (long)S,
        out + (size_t)b0 * S * D, nullptr, (long)S * D,
        2048, 2048, 16384, 768, 6, 8);
  }
}

// Round 5
// 407.998 us; speedup vs baseline: 1.0078x; 1.0078x over previous
//
#include <hip/hip_runtime.h>

typedef unsigned short u16;
typedef float  f32x4  __attribute__((ext_vector_type(4)));
typedef unsigned short u16x4 __attribute__((ext_vector_type(4)));
typedef short  bf16x8 __attribute__((ext_vector_type(8)));

__device__ __forceinline__ u16 f2bf(float f) {
  unsigned x = __builtin_bit_cast(unsigned, f);
  x += 0x7fffu + ((x >> 16) & 1u);           // RTN-even
  return (u16)(x >> 16);
}
__device__ __forceinline__ float bf2f(u16 u) {
  return __builtin_bit_cast(float, (unsigned)u << 16);
}

// raw s_barrier with compiler memory fences (no vmcnt drain!)
#define BARRIER()                          \
  do {                                     \
    asm volatile("" ::: "memory");         \
    __builtin_amdgcn_s_barrier();          \
    asm volatile("" ::: "memory");         \
  } while (0)

// ---------------- split fp32 -> (hi,lo) bf16 ----------------
__global__ void split_kernel(const float* __restrict__ x, u16* __restrict__ xh,
                             u16* __restrict__ xl, int n4) {
  int i = blockIdx.x * blockDim.x + threadIdx.x;
  int stride = gridDim.x * blockDim.x;
  for (; i < n4; i += stride) {
    f32x4 v = ((const f32x4*)x)[i];
    u16x4 h, l;
#pragma unroll
    for (int j = 0; j < 4; ++j) {
      u16 hh = f2bf(v[j]);
      h[j] = hh;
      l[j] = f2bf(v[j] - bf2f(hh));
    }
    ((u16x4*)xh)[i] = h;
    ((u16x4*)xl)[i] = l;
  }
}

// ---------------- transpose + split (for Wv) ----------------
__global__ void transpose_split_kernel(const float* __restrict__ W,
                                       u16* __restrict__ Th, u16* __restrict__ Tl) {
  int i = blockIdx.x * 256 + threadIdx.x;    // exactly 768*768 threads
  int h = i / 768, d = i % 768;
  float v = W[d * 768 + h];
  u16 hi = f2bf(v);
  Th[i] = hi;
  Tl[i] = f2bf(v - bf2f(hi));
}

// ---------------- GEMM: C = A * B^T ----------------
// 128x128 tile, BK=32, 4 waves (2x2 of 64x64), 16x16x32 bf16 MFMA.
// T4 counted-vmcnt double-buffer: stage k+1 into buf^1, then
// s_waitcnt vmcnt(N) (N = loads just issued -> waits only for tile k),
// raw s_barrier, compute, raw s_barrier. Next-tile loads stay in flight
// across both barriers (never drain to 0 in steady state).
// Bank swizzle: LDS chunk c of row r holds global k-chunk c ^ ((r>>1)&3).
// XCD-chunk bijective blockIdx remap (m204) for L2 locality.
// EPI: 0 = f32 store (+causal mask), 1 = split bf16 pair, 2 = bf16
// KROW: 0 = full K; 1 = K_eff=(ti+1)*128 (causal PV)
#define GLL16(g, l)                                                              \
  __builtin_amdgcn_global_load_lds(                                              \
      (const __attribute__((address_space(1))) unsigned int*)(g),                \
      (__attribute__((address_space(3))) unsigned int*)(l), 16, 0, 0)

template <int SPLIT, int EPI, int CAUSAL, int KROW>
__global__ __launch_bounds__(256, 2) void gemm_k(
    const u16* __restrict__ Ah, const u16* __restrict__ Al, long sAb,
    const u16* __restrict__ Bh, const u16* __restrict__ Bl, long sBb,
    void* __restrict__ Cv, void* __restrict__ C2v, long sCb,
    int K, int lda, int ldb, int ldc, int gx, int gy) {
  // ---- bijective XCD-chunk remap ----
  const int nwg = gridDim.x;
  const int orig = blockIdx.x;
  const int q8 = nwg >> 3, r8 = nwg & 7;
  const int xcd = orig & 7, pos = orig >> 3;
  const int wgid = (xcd < r8 ? xcd * (q8 + 1) : r8 * (q8 + 1) + (xcd - r8) * q8) + pos;
  const int tj = wgid % gx;
  const int rest = wgid / gx;
  const int ti = rest % gy;
  const int zb = rest / gy;
  if (CAUSAL && tj > ti) return;

  const u16* pAh = Ah + (size_t)zb * sAb;
  const u16* pBh = Bh + (size_t)zb * sBb;
  const u16* pAl = SPLIT ? Al + (size_t)zb * sAb : nullptr;
  const u16* pBl = SPLIT ? Bl + (size_t)zb * sBb : nullptr;

  __shared__ __align__(16) u16 As[2][SPLIT ? 2 : 1][4096];  // [buf][hi/lo][128r x 32k]
  __shared__ __align__(16) u16 Bs[2][SPLIT ? 2 : 1][4096];

  const int t = threadIdx.x, w = t >> 6, l = t & 63;
  const int wr = w >> 1, wc = w & 1;
  const int lr = l & 15, lk = l >> 4;

  // staging: thread t -> LDS row t>>2, chunk t&3; global k-chunk is XOR-swizzled
  const int srow = t >> 2;
  const int sk8 = ((t & 3) ^ ((srow >> 1) & 3)) * 8;
  // swizzled chunk offset for fragment reads (row-bits come only from lr)
  const int ck = ((lk ^ ((lr >> 1) & 3)) << 3);

  const size_t aOff0 = (size_t)(ti * 128 + srow) * lda + sk8;
  const size_t aOff1 = (size_t)(ti * 128 + 64 + srow) * lda + sk8;
  const size_t bOff0 = (size_t)(tj * 128 + srow) * ldb + sk8;
  const size_t bOff1 = (size_t)(tj * 128 + 64 + srow) * ldb + sk8;

  const int Keff = KROW ? (ti + 1) * 128 : K;
  const int nsteps = Keff >> 5;

  auto stage = [&](int bu, int kk) {
    const int kb = kk * 32;
    GLL16(pAh + aOff0 + kb, &As[bu][0][w * 512]);
    GLL16(pAh + aOff1 + kb, &As[bu][0][2048 + w * 512]);
    GLL16(pBh + bOff0 + kb, &Bs[bu][0][w * 512]);
    GLL16(pBh + bOff1 + kb, &Bs[bu][0][2048 + w * 512]);
    if constexpr (SPLIT) {
      GLL16(pAl + aOff0 + kb, &As[bu][1][w * 512]);
      GLL16(pAl + aOff1 + kb, &As[bu][1][2048 + w * 512]);
      GLL16(pBl + bOff0 + kb, &Bs[bu][1][w * 512]);
      GLL16(pBl + bOff1 + kb, &Bs[bu][1][2048 + w * 512]);
    }
  };

  f32x4 acc[4][4] = {};

  stage(0, 0);
  int buf = 0;
  for (int kk = 0; kk < nsteps; ++kk) {
    if (kk + 1 < nsteps) {
      stage(buf ^ 1, kk + 1);  // 8 (split) / 4 loads fly across the barriers
      if constexpr (SPLIT) asm volatile("s_waitcnt vmcnt(8)" ::: "memory");
      else                 asm volatile("s_waitcnt vmcnt(4)" ::: "memory");
    } else {
      asm volatile("s_waitcnt vmcnt(0)" ::: "memory");
    }
    BARRIER();  // all waves' tile-k loads landed

    bf16x8 ah[4], bh[4], al[4], bl[4];
#pragma unroll
    for (int mi = 0; mi < 4; ++mi) {
      const int ae = (wr * 64 + mi * 16 + lr) * 32 + ck;
      const int be = (wc * 64 + mi * 16 + lr) * 32 + ck;
      ah[mi] = *(const bf16x8*)&As[buf][0][ae];
      bh[mi] = *(const bf16x8*)&Bs[buf][0][be];
      if constexpr (SPLIT) {
        al[mi] = *(const bf16x8*)&As[buf][1][ae];
        bl[mi] = *(const bf16x8*)&Bs[buf][1][be];
      }
    }
#pragma unroll
    for (int mi = 0; mi < 4; ++mi)
#pragma unroll
      for (int ni = 0; ni < 4; ++ni) {
        acc[mi][ni] = __builtin_amdgcn_mfma_f32_16x16x32_bf16(ah[mi], bh[ni], acc[mi][ni], 0, 0, 0);
        if constexpr (SPLIT) {
          acc[mi][ni] = __builtin_amdgcn_mfma_f32_16x16x32_bf16(ah[mi], bl[ni], acc[mi][ni], 0, 0, 0);
          acc[mi][ni] = __builtin_amdgcn_mfma_f32_16x16x32_bf16(al[mi], bh[ni], acc[mi][ni], 0, 0, 0);
        }
      }
    BARRIER();  // all waves done reading buf before next stage overwrites it
    buf ^= 1;
  }

  // epilogue: C/D layout col = lane&15, row = (lane>>4)*4 + reg  [m89-verified]
#pragma unroll
  for (int mi = 0; mi < 4; ++mi)
#pragma unroll
    for (int ni = 0; ni < 4; ++ni)
#pragma unroll
      for (int r = 0; r < 4; ++r) {
        const int row = ti * 128 + wr * 64 + mi * 16 + lk * 4 + r;
        const int col = tj * 128 + wc * 64 + ni * 16 + lr;
        float v = acc[mi][ni][r];
        if (CAUSAL && col > row) v = -1e30f;
        const size_t idx = (size_t)zb * sCb + (size_t)row * ldc + col;
        if (EPI == 0) {
          ((float*)Cv)[idx] = v;
        } else if (EPI == 1) {
          u16 hv = f2bf(v);
          ((u16*)Cv)[idx] = hv;
          ((u16*)C2v)[idx] = f2bf(v - bf2f(hv));
        } else {
          ((u16*)Cv)[idx] = f2bf(v);
        }
      }
}

// ---------------- causal row softmax: scores f32 -> P bf16 ----------------
__global__ __launch_bounds__(256) void softmax_kernel(const float* __restrict__ S,
                                                      u16* __restrict__ P,
                                                      long sSb, long sPb) {
  const int wid = blockIdx.x * 4 + (threadIdx.x >> 6);  // one wave per row
  const int l = threadIdx.x & 63;
  const int zb = wid >> 11;
  const int i = wid & 2047;
  const float* row = S + (size_t)zb * sSb + (size_t)i * 2048;
  u16* prow = P + (size_t)zb * sPb + (size_t)i * 2048;
  const int Tend = ((i >> 7) + 1) << 7;  // multiple of 128
  const int nch = (Tend + 255) >> 8;

  f32x4 vb[8];
  float mx = -3e38f;
  for (int c = 0; c < nch; ++c) {
    const int j = c * 256 + l * 4;
    f32x4 v;
    if (j < Tend) v = *(const f32x4*)(row + j);
    else { v[0] = v[1] = v[2] = v[3] = -3e38f; }
    vb[c] = v;
    mx = fmaxf(mx, fmaxf(fmaxf(v[0], v[1]), fmaxf(v[2], v[3])));
  }
#pragma unroll
  for (int s = 32; s; s >>= 1) mx = fmaxf(mx, __shfl_xor(mx, s));

  float sum = 0.f;
  for (int c = 0; c < nch; ++c) {
    f32x4 v = vb[c];
#pragma unroll
    for (int j = 0; j < 4; ++j) {
      float e = expf(v[j] - mx);  // -1e30/-3e38 -> 0
      v[j] = e;
      sum += e;
    }
    vb[c] = v;
  }
#pragma unroll
  for (int s = 32; s; s >>= 1) sum += __shfl_xor(sum, s);
  const float inv = 1.f / sum;

  for (int c = 0; c < nch; ++c) {
    const int j = c * 256 + l * 4;
    if (j < Tend) {
      f32x4 v = vb[c];
      u16x4 o;
#pragma unroll
      for (int q = 0; q < 4; ++q) o[q] = f2bf(v[q] * inv);
      *(u16x4*)(prow + j) = o;
    }
  }
}

// ---------------- orchestration ----------------
extern "C" void kernel_launch(void* const* d_in, const int* in_sizes, int n_in,
                              void* d_out, int out_size, void* d_ws, size_t ws_size,
                              hipStream_t stream) {
  const float* x  = (const float*)d_in[0];
  const float* Wq = (const float*)d_in[1];
  const float* Wk = (const float*)d_in[2];
  const float* Wv = (const float*)d_in[3];
  float* out = (float*)d_out;

  const int S = 2048, D = 768;
  const size_t ND = (size_t)8 * S * D;        // 12.58M
  const size_t NW = (size_t)D * D;            // 589824

  char* ws = (char*)d_ws;
  size_t off = 0;
  auto alloc = [&](size_t bytes) { size_t o = off; off = (off + bytes + 255) & ~(size_t)255; return o; };

  u16* xh  = (u16*)(ws + alloc(ND * 2));
  u16* xl  = (u16*)(ws + alloc(ND * 2));
  u16* qh  = (u16*)(ws + alloc(ND * 2));
  u16* ql  = (u16*)(ws + alloc(ND * 2));
  u16* vt  = (u16*)(ws + alloc(ND * 2));
  u16* wqh = (u16*)(ws + alloc(NW * 2));
  u16* wql = (u16*)(ws + alloc(NW * 2));
  u16* wkh = (u16*)(ws + alloc(NW * 2));
  u16* wkl = (u16*)(ws + alloc(NW * 2));
  u16* wvth = (u16*)(ws + alloc(NW * 2));
  u16* wvtl = (u16*)(ws + alloc(NW * 2));
  u16* mth = (u16*)(ws + alloc(NW * 2));
  u16* mtl = (u16*)(ws + alloc(NW * 2));
  const size_t fixed = off;

  const size_t perBatch = (size_t)S * S * 4 + (size_t)S * S * 2 + 512;  // scores f32 + P bf16
  int g = 0;
  for (int cand = 8; cand >= 1; cand >>= 1)
    if (fixed + (size_t)cand * perBatch <= ws_size) { g = cand; break; }
  if (!g) return;

  float* sc = (float*)(ws + alloc((size_t)g * S * S * 4));
  u16*   P  = (u16*)(ws + alloc((size_t)g * S * S * 2));

  // prep: splits
  split_kernel<<<2048, 256, 0, stream>>>(x, xh, xl, (int)(ND / 4));
  split_kernel<<<576, 256, 0, stream>>>(Wq, wqh, wql, (int)(NW / 4));
  split_kernel<<<576, 256, 0, stream>>>(Wk, wkh, wkl, (int)(NW / 4));
  transpose_split_kernel<<<2304, 256, 0, stream>>>(Wv, wvth, wvtl);

  // Mt[e][d] = sum_h Wk[e][h] * Wq[d][h]   (= (Wq Wk^T)^T), split output
  gemm_k<1, 1, 0, 0><<<36, 256, 0, stream>>>(
      wkh, wkl, 0, wqh, wql, 0, mth, mtl, 0, 768, 768, 768, 768, 6, 6);

  // q'[s][j] = sum_d x[s][d] * Mt[j][d], split output
  gemm_k<1, 1, 0, 0><<<768, 256, 0, stream>>>(
      xh, xl, 0, mth, mtl, 0, qh, ql, 0, 768, 768, 768, 768, 6, 128);

  // vt[h][b*2048+s] = sum_d WvT[h][d] * x[s][d]  (bf16 out)
  gemm_k<0, 2, 0, 0><<<768, 256, 0, stream>>>(
      wvth, nullptr, 0, xh, nullptr, 0, vt, nullptr, 0, 768, 768, 768, 16384, 128, 6);

  for (int b0 = 0; b0 < 8; b0 += g) {
    // scores[b][i][j] = q'[b,i] . x[b,j]  (causal tiles only, mask to -1e30)
    gemm_k<1, 0, 1, 0><<<16 * 16 * g, 256, 0, stream>>>(
        qh + (size_t)b0 * S * D, ql + (size_t)b0 * S * D, (long)S * D,
        xh + (size_t)b0 * S * D, xl + (size_t)b0 * S * D, (long)S * D,
        sc, nullptr, (long)S * S, 768, 768, 768, 2048, 16, 16);

    softmax_kernel<<<g * 512, 256, 0, stream>>>(sc, P, (long)S * S, (long)S * S);

    // out[b][i][h] = sum_{j<Tend} P[b][i][j] * vt[h][b*2048+j]
    gemm_k<0, 0, 0, 1><<<6 * 16 * g, 256, 0, stream>>>(
        P, nullptr, (long)S * S,
        vt + (size_t)b0 * S, nullptr, (long)S,
        out + (size_t)b0 * S * D, nullptr, (long)S * D,
        2048, 2048, 16384, 768, 6, 16);
  }
}

// Round 6
// 382.806 us; speedup vs baseline: 1.0741x; 1.0658x over previous
//
#include <hip/hip_runtime.h>

typedef unsigned short u16;
typedef float  f32x4  __attribute__((ext_vector_type(4)));
typedef unsigned short u16x4 __attribute__((ext_vector_type(4)));
typedef short  bf16x8 __attribute__((ext_vector_type(8)));

__device__ __forceinline__ u16 f2bf(float f) {
  unsigned x = __builtin_bit_cast(unsigned, f);
  x += 0x7fffu + ((x >> 16) & 1u);           // RTN-even
  return (u16)(x >> 16);
}
__device__ __forceinline__ float bf2f(u16 u) {
  return __builtin_bit_cast(float, (unsigned)u << 16);
}

// raw s_barrier with compiler memory fences (no vmcnt drain)
#define BARRIER()                          \
  do {                                     \
    asm volatile("" ::: "memory");         \
    __builtin_amdgcn_s_barrier();          \
    asm volatile("" ::: "memory");         \
  } while (0)

// ---------------- fused prep: split x/Wq/Wk (hi,lo) + transpose-split Wv(hi) --
__global__ __launch_bounds__(256) void prep_kernel(
    const float* __restrict__ x, const float* __restrict__ Wq,
    const float* __restrict__ Wk, const float* __restrict__ Wv,
    u16* __restrict__ xh, u16* __restrict__ xl,
    u16* __restrict__ wqh, u16* __restrict__ wql,
    u16* __restrict__ wkh, u16* __restrict__ wkl,
    u16* __restrict__ wvth) {
  const int bid = blockIdx.x, tid = threadIdx.x;
  if (bid < 13440) {  // vector hi/lo splits
    const float* src;
    u16 *dh, *dl;
    int i;
    if (bid < 12288) { src = x;  dh = xh;  dl = xl;  i = bid * 256 + tid; }
    else if (bid < 12864) { src = Wq; dh = wqh; dl = wql; i = (bid - 12288) * 256 + tid; }
    else { src = Wk; dh = wkh; dl = wkl; i = (bid - 12864) * 256 + tid; }
    f32x4 v = ((const f32x4*)src)[i];
    u16x4 h, l;
#pragma unroll
    for (int j = 0; j < 4; ++j) {
      u16 hh = f2bf(v[j]);
      h[j] = hh;
      l[j] = f2bf(v[j] - bf2f(hh));
    }
    ((u16x4*)dh)[i] = h;
    ((u16x4*)dl)[i] = l;
  } else {  // Wv transpose (hi only): 2304 blocks
    int i = (bid - 13440) * 256 + tid;   // 589824 total
    int h = i / 768, d = i % 768;
    wvth[i] = f2bf(Wv[d * 768 + h]);
  }
}

// ---------------- GEMM: C = A * B^T ----------------
// 128xBN tile, BK=32, 4 waves (2x2; wave = 64 x BN/2), 16x16x32 bf16 MFMA.
// T4 counted-vmcnt double-buffer; raw barriers (loads stay in flight).
// Bank swizzle: LDS chunk c of row r holds global k-chunk c ^ ((r>>1)&3).
// XCD-chunk bijective blockIdx remap (m204).
// EPI: 0 = f32 store (+causal mask), 1 = split bf16 pair, 2 = bf16
// KROW: 0 = full K; 1 = K_eff=(ti+1)*128 (causal PV)
// BN: 128 or 64 (64 -> higher occupancy for latency-bound kernels)
#define GLL16(g, l)                                                              \
  __builtin_amdgcn_global_load_lds(                                              \
      (const __attribute__((address_space(1))) unsigned int*)(g),                \
      (__attribute__((address_space(3))) unsigned int*)(l), 16, 0, 0)

template <int SPLIT, int EPI, int CAUSAL, int KROW, int BN>
__global__ __launch_bounds__(256, 2) void gemm_k(
    const u16* __restrict__ Ah, const u16* __restrict__ Al, long sAb,
    const u16* __restrict__ Bh, const u16* __restrict__ Bl, long sBb,
    void* __restrict__ Cv, void* __restrict__ C2v, long sCb,
    int K, int lda, int ldb, int ldc, int gx, int gy) {
  // ---- bijective XCD-chunk remap ----
  const int nwg = gridDim.x;
  const int orig = blockIdx.x;
  const int q8 = nwg >> 3, r8 = nwg & 7;
  const int xcd = orig & 7, pos = orig >> 3;
  const int wgid = (xcd < r8 ? xcd * (q8 + 1) : r8 * (q8 + 1) + (xcd - r8) * q8) + pos;
  const int tj = wgid % gx;
  const int rest = wgid / gx;
  const int ti = rest % gy;
  const int zb = rest / gy;
  if (CAUSAL && tj > ti) return;

  const u16* pAh = Ah + (size_t)zb * sAb;
  const u16* pBh = Bh + (size_t)zb * sBb;
  const u16* pAl = SPLIT ? Al + (size_t)zb * sAb : nullptr;
  const u16* pBl = SPLIT ? Bl + (size_t)zb * sBb : nullptr;

  __shared__ __align__(16) u16 As[2][SPLIT ? 2 : 1][4096];     // [buf][hi/lo][128r x 32k]
  __shared__ __align__(16) u16 Bs[2][SPLIT ? 2 : 1][BN * 32];  // [buf][hi/lo][BNr x 32k]

  const int t = threadIdx.x, w = t >> 6, l = t & 63;
  const int wr = w >> 1, wc = w & 1;
  const int lr = l & 15, lk = l >> 4;
  constexpr int NI = BN / 32;                 // 4 (BN=128) or 2 (BN=64)
  constexpr int LPS = (2 + BN / 64) * (1 + SPLIT);  // loads per stage: 8/6/4/3

  // staging: thread t -> LDS row t>>2, chunk t&3; global k-chunk is XOR-swizzled
  const int srow = t >> 2;
  const int sk8 = ((t & 3) ^ ((srow >> 1) & 3)) * 8;
  // swizzled chunk offset for fragment reads (row-bits come only from lr)
  const int ck = ((lk ^ ((lr >> 1) & 3)) << 3);

  const size_t aOff0 = (size_t)(ti * 128 + srow) * lda + sk8;
  const size_t aOff1 = (size_t)(ti * 128 + 64 + srow) * lda + sk8;
  const size_t bOff0 = (size_t)(tj * BN + srow) * ldb + sk8;
  const size_t bOff1 = (size_t)(tj * BN + 64 + srow) * ldb + sk8;  // BN=128 only

  const int Keff = KROW ? (ti + 1) * 128 : K;
  const int nsteps = Keff >> 5;

  auto stage = [&](int bu, int kk) {
    const int kb = kk * 32;
    GLL16(pAh + aOff0 + kb, &As[bu][0][w * 512]);
    GLL16(pAh + aOff1 + kb, &As[bu][0][2048 + w * 512]);
    GLL16(pBh + bOff0 + kb, &Bs[bu][0][w * 512]);
    if constexpr (BN == 128) GLL16(pBh + bOff1 + kb, &Bs[bu][0][2048 + w * 512]);
    if constexpr (SPLIT) {
      GLL16(pAl + aOff0 + kb, &As[bu][1][w * 512]);
      GLL16(pAl + aOff1 + kb, &As[bu][1][2048 + w * 512]);
      GLL16(pBl + bOff0 + kb, &Bs[bu][1][w * 512]);
      if constexpr (BN == 128) GLL16(pBl + bOff1 + kb, &Bs[bu][1][2048 + w * 512]);
    }
  };

  f32x4 acc[4][NI] = {};

  stage(0, 0);
  int buf = 0;
  for (int kk = 0; kk < nsteps; ++kk) {
    if (kk + 1 < nsteps) {
      stage(buf ^ 1, kk + 1);  // next-tile loads fly across the barriers
      if constexpr (LPS == 8)      asm volatile("s_waitcnt vmcnt(8)" ::: "memory");
      else if constexpr (LPS == 6) asm volatile("s_waitcnt vmcnt(6)" ::: "memory");
      else if constexpr (LPS == 4) asm volatile("s_waitcnt vmcnt(4)" ::: "memory");
      else                         asm volatile("s_waitcnt vmcnt(3)" ::: "memory");
    } else {
      asm volatile("s_waitcnt vmcnt(0)" ::: "memory");
    }
    BARRIER();  // all waves' tile-k loads landed

    bf16x8 ah[4], bh[NI], al[4], bl[NI];
#pragma unroll
    for (int mi = 0; mi < 4; ++mi) {
      const int ae = (wr * 64 + mi * 16 + lr) * 32 + ck;
      ah[mi] = *(const bf16x8*)&As[buf][0][ae];
      if constexpr (SPLIT) al[mi] = *(const bf16x8*)&As[buf][1][ae];
    }
#pragma unroll
    for (int ni = 0; ni < NI; ++ni) {
      const int be = (wc * (BN / 2) + ni * 16 + lr) * 32 + ck;
      bh[ni] = *(const bf16x8*)&Bs[buf][0][be];
      if constexpr (SPLIT) bl[ni] = *(const bf16x8*)&Bs[buf][1][be];
    }
#pragma unroll
    for (int mi = 0; mi < 4; ++mi)
#pragma unroll
      for (int ni = 0; ni < NI; ++ni) {
        acc[mi][ni] = __builtin_amdgcn_mfma_f32_16x16x32_bf16(ah[mi], bh[ni], acc[mi][ni], 0, 0, 0);
        if constexpr (SPLIT) {
          acc[mi][ni] = __builtin_amdgcn_mfma_f32_16x16x32_bf16(ah[mi], bl[ni], acc[mi][ni], 0, 0, 0);
          acc[mi][ni] = __builtin_amdgcn_mfma_f32_16x16x32_bf16(al[mi], bh[ni], acc[mi][ni], 0, 0, 0);
        }
      }
    BARRIER();  // all waves done reading buf before next stage overwrites it
    buf ^= 1;
  }

  // epilogue: C/D layout col = lane&15, row = (lane>>4)*4 + reg  [m89-verified]
#pragma unroll
  for (int mi = 0; mi < 4; ++mi)
#pragma unroll
    for (int ni = 0; ni < NI; ++ni)
#pragma unroll
      for (int r = 0; r < 4; ++r) {
        const int row = ti * 128 + wr * 64 + mi * 16 + lk * 4 + r;
        const int col = tj * BN + wc * (BN / 2) + ni * 16 + lr;
        float v = acc[mi][ni][r];
        if (CAUSAL && col > row) v = -1e30f;
        const size_t idx = (size_t)zb * sCb + (size_t)row * ldc + col;
        if (EPI == 0) {
          ((float*)Cv)[idx] = v;
        } else if (EPI == 1) {
          u16 hv = f2bf(v);
          ((u16*)Cv)[idx] = hv;
          ((u16*)C2v)[idx] = f2bf(v - bf2f(hv));
        } else {
          ((u16*)Cv)[idx] = f2bf(v);
        }
      }
}

// ---------------- causal row softmax: scores f32 -> P bf16 ----------------
__global__ __launch_bounds__(256) void softmax_kernel(const float* __restrict__ S,
                                                      u16* __restrict__ P,
                                                      long sSb, long sPb) {
  const int wid = blockIdx.x * 4 + (threadIdx.x >> 6);  // one wave per row
  const int l = threadIdx.x & 63;
  const int zb = wid >> 11;
  const int i = wid & 2047;
  const float* row = S + (size_t)zb * sSb + (size_t)i * 2048;
  u16* prow = P + (size_t)zb * sPb + (size_t)i * 2048;
  const int Tend = ((i >> 7) + 1) << 7;  // multiple of 128
  const int nch = (Tend + 255) >> 8;

  f32x4 vb[8];
  float mx = -3e38f;
  for (int c = 0; c < nch; ++c) {
    const int j = c * 256 + l * 4;
    f32x4 v;
    if (j < Tend) v = *(const f32x4*)(row + j);
    else { v[0] = v[1] = v[2] = v[3] = -3e38f; }
    vb[c] = v;
    mx = fmaxf(mx, fmaxf(fmaxf(v[0], v[1]), fmaxf(v[2], v[3])));
  }
#pragma unroll
  for (int s = 32; s; s >>= 1) mx = fmaxf(mx, __shfl_xor(mx, s));

  float sum = 0.f;
  for (int c = 0; c < nch; ++c) {
    f32x4 v = vb[c];
#pragma unroll
    for (int j = 0; j < 4; ++j) {
      float e = expf(v[j] - mx);  // -1e30/-3e38 -> 0
      v[j] = e;
      sum += e;
    }
    vb[c] = v;
  }
#pragma unroll
  for (int s = 32; s; s >>= 1) sum += __shfl_xor(sum, s);
  const float inv = 1.f / sum;

  for (int c = 0; c < nch; ++c) {
    const int j = c * 256 + l * 4;
    if (j < Tend) {
      f32x4 v = vb[c];
      u16x4 o;
#pragma unroll
      for (int q = 0; q < 4; ++q) o[q] = f2bf(v[q] * inv);
      *(u16x4*)(prow + j) = o;
    }
  }
}

// ---------------- orchestration ----------------
extern "C" void kernel_launch(void* const* d_in, const int* in_sizes, int n_in,
                              void* d_out, int out_size, void* d_ws, size_t ws_size,
                              hipStream_t stream) {
  const float* x  = (const float*)d_in[0];
  const float* Wq = (const float*)d_in[1];
  const float* Wk = (const float*)d_in[2];
  const float* Wv = (const float*)d_in[3];
  float* out = (float*)d_out;

  const int S = 2048, D = 768;
  const size_t ND = (size_t)8 * S * D;        // 12.58M
  const size_t NW = (size_t)D * D;            // 589824

  char* ws = (char*)d_ws;
  size_t off = 0;
  auto alloc = [&](size_t bytes) { size_t o = off; off = (off + bytes + 255) & ~(size_t)255; return o; };

  u16* xh  = (u16*)(ws + alloc(ND * 2));
  u16* xl  = (u16*)(ws + alloc(ND * 2));
  u16* qh  = (u16*)(ws + alloc(ND * 2));
  u16* ql  = (u16*)(ws + alloc(ND * 2));
  u16* vt  = (u16*)(ws + alloc(ND * 2));
  u16* wqh = (u16*)(ws + alloc(NW * 2));
  u16* wql = (u16*)(ws + alloc(NW * 2));
  u16* wkh = (u16*)(ws + alloc(NW * 2));
  u16* wkl = (u16*)(ws + alloc(NW * 2));
  u16* wvth = (u16*)(ws + alloc(NW * 2));
  u16* mth = (u16*)(ws + alloc(NW * 2));
  u16* mtl = (u16*)(ws + alloc(NW * 2));
  const size_t fixed = off;

  const size_t perBatch = (size_t)S * S * 4 + (size_t)S * S * 2 + 512;  // scores f32 + P bf16
  int g = 0;
  for (int cand = 8; cand >= 1; cand >>= 1)
    if (fixed + (size_t)cand * perBatch <= ws_size) { g = cand; break; }
  if (!g) return;

  float* sc = (float*)(ws + alloc((size_t)g * S * S * 4));
  u16*   P  = (u16*)(ws + alloc((size_t)g * S * S * 2));

  // fused prep: x/Wq/Wk hi-lo splits + Wv transpose (hi)
  prep_kernel<<<15744, 256, 0, stream>>>(x, Wq, Wk, Wv, xh, xl, wqh, wql, wkh, wkl, wvth);

  // Mt[e][d] = sum_h Wk[e][h] * Wq[d][h]   (= (Wq Wk^T)^T), split output, BN=64
  gemm_k<1, 1, 0, 0, 64><<<72, 256, 0, stream>>>(
      wkh, wkl, 0, wqh, wql, 0, mth, mtl, 0, 768, 768, 768, 768, 12, 6);

  // q'[s][j] = sum_d x[s][d] * Mt[j][d], split output, BN=64 (3 blocks/CU)
  gemm_k<1, 1, 0, 0, 64><<<1536, 256, 0, stream>>>(
      xh, xl, 0, mth, mtl, 0, qh, ql, 0, 768, 768, 768, 768, 12, 128);

  // vt[h][b*2048+s] = sum_d WvT[h][d] * x[s][d]  (bf16 out), BN=128
  gemm_k<0, 2, 0, 0, 128><<<768, 256, 0, stream>>>(
      wvth, nullptr, 0, xh, nullptr, 0, vt, nullptr, 0, 768, 768, 768, 16384, 128, 6);

  for (int b0 = 0; b0 < 8; b0 += g) {
    // scores[b][i][j] = q'[b,i] . x[b,j]  (causal tiles only, mask to -1e30)
    gemm_k<1, 0, 1, 0, 128><<<16 * 16 * g, 256, 0, stream>>>(
        qh + (size_t)b0 * S * D, ql + (size_t)b0 * S * D, (long)S * D,
        xh + (size_t)b0 * S * D, xl + (size_t)b0 * S * D, (long)S * D,
        sc, nullptr, (long)S * S, 768, 768, 768, 2048, 16, 16);

    softmax_kernel<<<g * 512, 256, 0, stream>>>(sc, P, (long)S * S, (long)S * S);

    // out[b][i][h] = sum_{j<Tend} P[b][i][j] * vt[h][b*2048+j]  (BN=64, 6 blocks/CU)
    gemm_k<0, 0, 0, 1, 64><<<12 * 16 * g, 256, 0, stream>>>(
        P, nullptr, (long)S * S,
        vt + (size_t)b0 * S, nullptr, (long)S,
        out + (size_t)b0 * S * D, nullptr, (long)S * D,
        2048, 2048, 16384, 768, 12, 16);
  }
}

// Round 7
// 355.467 us; speedup vs baseline: 1.1567x; 1.0769x over previous
//
#include <hip/hip_runtime.h>

typedef unsigned short u16;
typedef float  f32x4  __attribute__((ext_vector_type(4)));
typedef unsigned short u16x4 __attribute__((ext_vector_type(4)));
typedef short  bf16x8 __attribute__((ext_vector_type(8)));

__device__ __forceinline__ u16 f2bf(float f) {
  unsigned x = __builtin_bit_cast(unsigned, f);
  x += 0x7fffu + ((x >> 16) & 1u);           // RTN-even
  return (u16)(x >> 16);
}
__device__ __forceinline__ float bf2f(u16 u) {
  return __builtin_bit_cast(float, (unsigned)u << 16);
}

// raw s_barrier with compiler memory fences (no vmcnt drain)
#define BARRIER()                          \
  do {                                     \
    asm volatile("" ::: "memory");         \
    __builtin_amdgcn_s_barrier();          \
    asm volatile("" ::: "memory");         \
  } while (0)

#define GLL16(g, l)                                                              \
  __builtin_amdgcn_global_load_lds(                                              \
      (const __attribute__((address_space(1))) unsigned int*)(g),                \
      (__attribute__((address_space(3))) unsigned int*)(l), 16, 0, 0)

// ---------------- fused prep: split x/Wq/Wk (hi,lo) + transpose-split Wv(hi) --
__global__ __launch_bounds__(256) void prep_kernel(
    const float* __restrict__ x, const float* __restrict__ Wq,
    const float* __restrict__ Wk, const float* __restrict__ Wv,
    u16* __restrict__ xh, u16* __restrict__ xl,
    u16* __restrict__ wqh, u16* __restrict__ wql,
    u16* __restrict__ wkh, u16* __restrict__ wkl,
    u16* __restrict__ wvth) {
  const int bid = blockIdx.x, tid = threadIdx.x;
  if (bid < 13440) {  // vector hi/lo splits
    const float* src;
    u16 *dh, *dl;
    int i;
    if (bid < 12288) { src = x;  dh = xh;  dl = xl;  i = bid * 256 + tid; }
    else if (bid < 12864) { src = Wq; dh = wqh; dl = wql; i = (bid - 12288) * 256 + tid; }
    else { src = Wk; dh = wkh; dl = wkl; i = (bid - 12864) * 256 + tid; }
    f32x4 v = ((const f32x4*)src)[i];
    u16x4 h, l;
#pragma unroll
    for (int j = 0; j < 4; ++j) {
      u16 hh = f2bf(v[j]);
      h[j] = hh;
      l[j] = f2bf(v[j] - bf2f(hh));
    }
    ((u16x4*)dh)[i] = h;
    ((u16x4*)dl)[i] = l;
  } else {  // Wv transpose (hi only): 2304 blocks
    int i = (bid - 13440) * 256 + tid;   // 589824 total
    int h = i / 768, d = i % 768;
    wvth[i] = f2bf(Wv[d * 768 + h]);
  }
}

// ---------------- GEMM body: C(128 x BN) = A * B^T ----------------
// BK=32, 4 waves (2x2; wave = 64 x BN/2), 16x16x32 bf16 MFMA.
// T4 counted-vmcnt double-buffer; raw barriers (loads stay in flight).
// Bank swizzle: LDS chunk c of row r holds global k-chunk c ^ ((r>>1)&3).
// EPI: 0 = f32 store (+causal mask), 1 = split bf16 pair, 2 = bf16
// LDS layout: As slabs [2][NB][4096] then Bs slabs [2][NB][BN*32] (u16).
template <int SPLIT, int EPI, int CAUSAL, int KROW, int BN>
__device__ __forceinline__ void gemm_body(
    u16* __restrict__ lds,
    const u16* __restrict__ pAh, const u16* __restrict__ pAl,
    const u16* __restrict__ pBh, const u16* __restrict__ pBl,
    void* __restrict__ Cv, void* __restrict__ C2v, size_t cbase,
    int K, int lda, int ldb, int ldc, int ti, int tj) {
  constexpr int NB = SPLIT ? 2 : 1;
  constexpr int BSZ = BN * 32;
  u16* As = lds;                    // [2][NB][4096]
  u16* Bs = lds + 2 * NB * 4096;    // [2][NB][BSZ]

  const int t = threadIdx.x, w = t >> 6, l = t & 63;
  const int wr = w >> 1, wc = w & 1;
  const int lr = l & 15, lk = l >> 4;
  constexpr int NI = BN / 32;                       // 4 (BN=128) or 2 (BN=64)
  constexpr int LPS = (2 + BN / 64) * (1 + SPLIT);  // loads per stage: 8/6/4/3

  // staging: thread t -> LDS row t>>2, chunk t&3; global k-chunk is XOR-swizzled
  const int srow = t >> 2;
  const int sk8 = ((t & 3) ^ ((srow >> 1) & 3)) * 8;
  // swizzled chunk offset for fragment reads (row-bits come only from lr)
  const int ck = ((lk ^ ((lr >> 1) & 3)) << 3);

  const size_t aOff0 = (size_t)(ti * 128 + srow) * lda + sk8;
  const size_t aOff1 = (size_t)(ti * 128 + 64 + srow) * lda + sk8;
  const size_t bOff0 = (size_t)(tj * BN + srow) * ldb + sk8;
  const size_t bOff1 = (size_t)(tj * BN + 64 + srow) * ldb + sk8;  // BN=128 only

  const int Keff = KROW ? (ti + 1) * 128 : K;
  const int nsteps = Keff >> 5;

  auto stage = [&](int bu, int kk) {
    const int kb = kk * 32;
    GLL16(pAh + aOff0 + kb, As + (bu * NB) * 4096 + w * 512);
    GLL16(pAh + aOff1 + kb, As + (bu * NB) * 4096 + 2048 + w * 512);
    GLL16(pBh + bOff0 + kb, Bs + (bu * NB) * BSZ + w * 512);
    if constexpr (BN == 128) GLL16(pBh + bOff1 + kb, Bs + (bu * NB) * BSZ + 2048 + w * 512);
    if constexpr (SPLIT) {
      GLL16(pAl + aOff0 + kb, As + (bu * NB + 1) * 4096 + w * 512);
      GLL16(pAl + aOff1 + kb, As + (bu * NB + 1) * 4096 + 2048 + w * 512);
      GLL16(pBl + bOff0 + kb, Bs + (bu * NB + 1) * BSZ + w * 512);
      if constexpr (BN == 128) GLL16(pBl + bOff1 + kb, Bs + (bu * NB + 1) * BSZ + 2048 + w * 512);
    }
  };

  f32x4 acc[4][NI] = {};

  stage(0, 0);
  int buf = 0;
  for (int kk = 0; kk < nsteps; ++kk) {
    if (kk + 1 < nsteps) {
      stage(buf ^ 1, kk + 1);  // next-tile loads fly across the barriers
      if constexpr (LPS == 8)      asm volatile("s_waitcnt vmcnt(8)" ::: "memory");
      else if constexpr (LPS == 6) asm volatile("s_waitcnt vmcnt(6)" ::: "memory");
      else if constexpr (LPS == 4) asm volatile("s_waitcnt vmcnt(4)" ::: "memory");
      else                         asm volatile("s_waitcnt vmcnt(3)" ::: "memory");
    } else {
      asm volatile("s_waitcnt vmcnt(0)" ::: "memory");
    }
    BARRIER();  // all waves' tile-k loads landed

    bf16x8 ah[4], bh[NI], al[4], bl[NI];
#pragma unroll
    for (int mi = 0; mi < 4; ++mi) {
      const int ae = (buf * NB) * 4096 + (wr * 64 + mi * 16 + lr) * 32 + ck;
      ah[mi] = *(const bf16x8*)&As[ae];
      if constexpr (SPLIT) al[mi] = *(const bf16x8*)&As[ae + 4096];
    }
#pragma unroll
    for (int ni = 0; ni < NI; ++ni) {
      const int be = (buf * NB) * BSZ + (wc * (BN / 2) + ni * 16 + lr) * 32 + ck;
      bh[ni] = *(const bf16x8*)&Bs[be];
      if constexpr (SPLIT) bl[ni] = *(const bf16x8*)&Bs[be + BSZ];
    }
#pragma unroll
    for (int mi = 0; mi < 4; ++mi)
#pragma unroll
      for (int ni = 0; ni < NI; ++ni) {
        acc[mi][ni] = __builtin_amdgcn_mfma_f32_16x16x32_bf16(ah[mi], bh[ni], acc[mi][ni], 0, 0, 0);
        if constexpr (SPLIT) {
          acc[mi][ni] = __builtin_amdgcn_mfma_f32_16x16x32_bf16(ah[mi], bl[ni], acc[mi][ni], 0, 0, 0);
          acc[mi][ni] = __builtin_amdgcn_mfma_f32_16x16x32_bf16(al[mi], bh[ni], acc[mi][ni], 0, 0, 0);
        }
      }
    BARRIER();  // all waves done reading buf before next stage overwrites it
    buf ^= 1;
  }

  // epilogue: C/D layout col = lane&15, row = (lane>>4)*4 + reg  [m89-verified]
#pragma unroll
  for (int mi = 0; mi < 4; ++mi)
#pragma unroll
    for (int ni = 0; ni < NI; ++ni)
#pragma unroll
      for (int r = 0; r < 4; ++r) {
        const int row = ti * 128 + wr * 64 + mi * 16 + lk * 4 + r;
        const int col = tj * BN + wc * (BN / 2) + ni * 16 + lr;
        float v = acc[mi][ni][r];
        if (CAUSAL && col > row) v = -1e30f;
        const size_t idx = cbase + (size_t)row * ldc + col;
        if (EPI == 0) {
          ((float*)Cv)[idx] = v;
        } else if (EPI == 1) {
          u16 hv = f2bf(v);
          ((u16*)Cv)[idx] = hv;
          ((u16*)C2v)[idx] = f2bf(v - bf2f(hv));
        } else {
          ((u16*)Cv)[idx] = f2bf(v);
        }
      }
}

// ---------------- generic GEMM wrapper (XCD-chunk bijective remap, m204) ----
template <int SPLIT, int EPI, int CAUSAL, int KROW, int BN>
__global__ __launch_bounds__(256, 2) void gemm_k(
    const u16* __restrict__ Ah, const u16* __restrict__ Al, long sAb,
    const u16* __restrict__ Bh, const u16* __restrict__ Bl, long sBb,
    void* __restrict__ Cv, void* __restrict__ C2v, long sCb,
    int K, int lda, int ldb, int ldc, int gx, int gy) {
  __shared__ __align__(16) u16 lds[2 * (SPLIT ? 2 : 1) * (4096 + BN * 32)];
  const int nwg = gridDim.x;
  const int orig = blockIdx.x;
  const int q8 = nwg >> 3, r8 = nwg & 7;
  const int xcd = orig & 7, pos = orig >> 3;
  const int wgid = (xcd < r8 ? xcd * (q8 + 1) : r8 * (q8 + 1) + (xcd - r8) * q8) + pos;
  const int tj = wgid % gx;
  const int rest = wgid / gx;
  const int ti = rest % gy;
  const int zb = rest / gy;
  if (CAUSAL && tj > ti) return;
  gemm_body<SPLIT, EPI, CAUSAL, KROW, BN>(
      lds, Ah + (size_t)zb * sAb, SPLIT ? Al + (size_t)zb * sAb : nullptr,
      Bh + (size_t)zb * sBb, SPLIT ? Bl + (size_t)zb * sBb : nullptr,
      Cv, C2v, (size_t)zb * sCb, K, lda, ldb, ldc, ti, tj);
}

// ---------------- fused projection: q' (split, 3-pass) + vt (plain) ----------
// 1536 blocks @ 64KB LDS -> 2 blocks/CU -> exactly 3 full generations.
// Per x-row-tile sidx: sub 0..5 = q' col-tiles, sub 6..11 = vt row-tiles
// (q' A-reads and vt B-reads share the same x tiles -> L2 reuse per XCD chunk).
__global__ __launch_bounds__(256, 2) void proj_kernel(
    const u16* __restrict__ xh, const u16* __restrict__ xl,
    const u16* __restrict__ mth, const u16* __restrict__ mtl,
    const u16* __restrict__ wvth,
    u16* __restrict__ qh, u16* __restrict__ ql, u16* __restrict__ vt) {
  __shared__ __align__(16) u16 lds[32768];  // 64KB, shared by both variants
  const int orig = blockIdx.x;
  const int wgid = (orig & 7) * 192 + (orig >> 3);  // bijective (1536 % 8 == 0)
  const int sidx = wgid / 12, sub = wgid % 12;
  if (sub < 6) {
    // q'[s][j] = sum_d x[s][d] * Mt[j][d]  (split out)
    gemm_body<1, 1, 0, 0, 128>(lds, xh, xl, mth, mtl, qh, ql, 0,
                               768, 768, 768, 768, sidx, sub);
  } else {
    // vt[h][s] = sum_d WvT[h][d] * x[s][d]  (bf16 out)
    gemm_body<0, 2, 0, 0, 128>(lds, wvth, nullptr, xh, nullptr, vt, nullptr, 0,
                               768, 768, 768, 16384, sub - 6, sidx);
  }
}

// ---------------- causal row softmax: scores f32 -> P bf16 ----------------
__global__ __launch_bounds__(256) void softmax_kernel(const float* __restrict__ S,
                                                      u16* __restrict__ P,
                                                      long sSb, long sPb) {
  const int wid = blockIdx.x * 4 + (threadIdx.x >> 6);  // one wave per row
  const int l = threadIdx.x & 63;
  const int zb = wid >> 11;
  const int i = wid & 2047;
  const float* row = S + (size_t)zb * sSb + (size_t)i * 2048;
  u16* prow = P + (size_t)zb * sPb + (size_t)i * 2048;
  const int Tend = ((i >> 7) + 1) << 7;  // multiple of 128
  const int nch = (Tend + 255) >> 8;

  f32x4 vb[8];
  float mx = -3e38f;
  for (int c = 0; c < nch; ++c) {
    const int j = c * 256 + l * 4;
    f32x4 v;
    if (j < Tend) v = *(const f32x4*)(row + j);
    else { v[0] = v[1] = v[2] = v[3] = -3e38f; }
    vb[c] = v;
    mx = fmaxf(mx, fmaxf(fmaxf(v[0], v[1]), fmaxf(v[2], v[3])));
  }
#pragma unroll
  for (int s = 32; s; s >>= 1) mx = fmaxf(mx, __shfl_xor(mx, s));

  float sum = 0.f;
  for (int c = 0; c < nch; ++c) {
    f32x4 v = vb[c];
#pragma unroll
    for (int j = 0; j < 4; ++j) {
      float e = expf(v[j] - mx);  // -1e30/-3e38 -> 0
      v[j] = e;
      sum += e;
    }
    vb[c] = v;
  }
#pragma unroll
  for (int s = 32; s; s >>= 1) sum += __shfl_xor(sum, s);
  const float inv = 1.f / sum;

  for (int c = 0; c < nch; ++c) {
    const int j = c * 256 + l * 4;
    if (j < Tend) {
      f32x4 v = vb[c];
      u16x4 o;
#pragma unroll
      for (int q = 0; q < 4; ++q) o[q] = f2bf(v[q] * inv);
      *(u16x4*)(prow + j) = o;
    }
  }
}

// ---------------- orchestration ----------------
extern "C" void kernel_launch(void* const* d_in, const int* in_sizes, int n_in,
                              void* d_out, int out_size, void* d_ws, size_t ws_size,
                              hipStream_t stream) {
  const float* x  = (const float*)d_in[0];
  const float* Wq = (const float*)d_in[1];
  const float* Wk = (const float*)d_in[2];
  const float* Wv = (const float*)d_in[3];
  float* out = (float*)d_out;

  const int S = 2048, D = 768;
  const size_t ND = (size_t)8 * S * D;        // 12.58M
  const size_t NW = (size_t)D * D;            // 589824

  char* ws = (char*)d_ws;
  size_t off = 0;
  auto alloc = [&](size_t bytes) { size_t o = off; off = (off + bytes + 255) & ~(size_t)255; return o; };

  u16* xh  = (u16*)(ws + alloc(ND * 2));
  u16* xl  = (u16*)(ws + alloc(ND * 2));
  u16* qh  = (u16*)(ws + alloc(ND * 2));
  u16* ql  = (u16*)(ws + alloc(ND * 2));
  u16* vt  = (u16*)(ws + alloc(ND * 2));
  u16* wqh = (u16*)(ws + alloc(NW * 2));
  u16* wql = (u16*)(ws + alloc(NW * 2));
  u16* wkh = (u16*)(ws + alloc(NW * 2));
  u16* wkl = (u16*)(ws + alloc(NW * 2));
  u16* wvth = (u16*)(ws + alloc(NW * 2));
  u16* mth = (u16*)(ws + alloc(NW * 2));
  u16* mtl = (u16*)(ws + alloc(NW * 2));
  const size_t fixed = off;

  const size_t perBatch = (size_t)S * S * 4 + (size_t)S * S * 2 + 512;  // scores f32 + P bf16
  int g = 0;
  for (int cand = 8; cand >= 1; cand >>= 1)
    if (fixed + (size_t)cand * perBatch <= ws_size) { g = cand; break; }
  if (!g) return;

  float* sc = (float*)(ws + alloc((size_t)g * S * S * 4));
  u16*   P  = (u16*)(ws + alloc((size_t)g * S * S * 2));

  // fused prep: x/Wq/Wk hi-lo splits + Wv transpose (hi)
  prep_kernel<<<15744, 256, 0, stream>>>(x, Wq, Wk, Wv, xh, xl, wqh, wql, wkh, wkl, wvth);

  // Mt[e][d] = sum_h Wk[e][h] * Wq[d][h]   (= (Wq Wk^T)^T), split output, BN=64
  gemm_k<1, 1, 0, 0, 64><<<72, 256, 0, stream>>>(
      wkh, wkl, 0, wqh, wql, 0, mth, mtl, 0, 768, 768, 768, 768, 12, 6);

  // fused q' + vt (exactly 3 generations of 512 resident blocks)
  proj_kernel<<<1536, 256, 0, stream>>>(xh, xl, mth, mtl, wvth, qh, ql, vt);

  for (int b0 = 0; b0 < 8; b0 += g) {
    // scores[b][i][j] = q'[b,i] . x[b,j]  (causal tiles only, mask to -1e30)
    gemm_k<1, 0, 1, 0, 128><<<16 * 16 * g, 256, 0, stream>>>(
        qh + (size_t)b0 * S * D, ql + (size_t)b0 * S * D, (long)S * D,
        xh + (size_t)b0 * S * D, xl + (size_t)b0 * S * D, (long)S * D,
        sc, nullptr, (long)S * S, 768, 768, 768, 2048, 16, 16);

    softmax_kernel<<<g * 512, 256, 0, stream>>>(sc, P, (long)S * S, (long)S * S);

    // out[b][i][h] = sum_{j<Tend} P[b][i][j] * vt[h][b*2048+j]  (BN=64, 6 blocks/CU)
    gemm_k<0, 0, 0, 1, 64><<<12 * 16 * g, 256, 0, stream>>>(
        P, nullptr, (long)S * S,
        vt + (size_t)b0 * S, nullptr, (long)S,
        out + (size_t)b0 * S * D, nullptr, (long)S * D,
        2048, 2048, 16384, 768, 12, 16);
  }
}

// Round 8
// 239.985 us; speedup vs baseline: 1.7133x; 1.4812x over previous
//
#include <hip/hip_runtime.h>

typedef unsigned short u16;
typedef _Float16 f16;
typedef float  f32x4  __attribute__((ext_vector_type(4)));
typedef unsigned short u16x4 __attribute__((ext_vector_type(4)));
typedef f16    f16x8  __attribute__((ext_vector_type(8)));

__device__ __forceinline__ u16 f2h(float f) {
  f16 h = (f16)f;                      // RTN-even via v_cvt_f16_f32
  return __builtin_bit_cast(u16, h);
}

// raw s_barrier with compiler memory fences (no vmcnt drain)
#define BARRIER()                          \
  do {                                     \
    asm volatile("" ::: "memory");         \
    __builtin_amdgcn_s_barrier();          \
    asm volatile("" ::: "memory");         \
  } while (0)

#define GLL16(g, l)                                                              \
  __builtin_amdgcn_global_load_lds(                                              \
      (const __attribute__((address_space(1))) unsigned int*)(g),                \
      (__attribute__((address_space(3))) unsigned int*)(l), 16, 0, 0)

// ---------------- fused prep: fp16 casts of x/Wq/Wk + transposed Wv ----------
__global__ __launch_bounds__(256) void prep_kernel(
    const float* __restrict__ x, const float* __restrict__ Wq,
    const float* __restrict__ Wk, const float* __restrict__ Wv,
    u16* __restrict__ xf, u16* __restrict__ wq16,
    u16* __restrict__ wk16, u16* __restrict__ wvt16) {
  const int bid = blockIdx.x, tid = threadIdx.x;
  if (bid < 13440) {  // straight f32 -> fp16 casts, vectorized
    const float* src;
    u16* dst;
    int i;
    if (bid < 12288) { src = x;  dst = xf;   i = bid * 256 + tid; }
    else if (bid < 12864) { src = Wq; dst = wq16; i = (bid - 12288) * 256 + tid; }
    else { src = Wk; dst = wk16; i = (bid - 12864) * 256 + tid; }
    f32x4 v = ((const f32x4*)src)[i];
    u16x4 h;
#pragma unroll
    for (int j = 0; j < 4; ++j) h[j] = f2h(v[j]);
    ((u16x4*)dst)[i] = h;
  } else {  // Wv transpose: 2304 blocks, 589824 elems
    int i = (bid - 13440) * 256 + tid;
    int h = i / 768, d = i % 768;
    wvt16[i] = f2h(Wv[d * 768 + h]);
  }
}

// ---------------- GEMM body: C(128 x BN) = A * B^T  (fp16 MFMA) -------------
// BK=32, 4 waves (2x2; wave = 64 x BN/2), 16x16x32 f16 MFMA.
// T4 counted-vmcnt double-buffer; raw barriers (loads stay in flight).
// Bank swizzle: LDS chunk c of row r holds global k-chunk c ^ ((r>>1)&3).
// EPI: 0 = f32 store (+causal mask), 2 = fp16 store
// LDS layout: As [2][4096] u16, then Bs [2][BN*32] u16.
template <int EPI, int CAUSAL, int KROW, int BN>
__device__ __forceinline__ void gemm_body(
    u16* __restrict__ lds,
    const u16* __restrict__ pA, const u16* __restrict__ pB,
    void* __restrict__ Cv, size_t cbase,
    int K, int lda, int ldb, int ldc, int ti, int tj) {
  constexpr int BSZ = BN * 32;
  u16* As = lds;                 // [2][4096]
  u16* Bs = lds + 2 * 4096;      // [2][BSZ]

  const int t = threadIdx.x, w = t >> 6, l = t & 63;
  const int wr = w >> 1, wc = w & 1;
  const int lr = l & 15, lk = l >> 4;
  constexpr int NI = BN / 32;              // 4 (BN=128) or 2 (BN=64)
  constexpr int LPS = 2 + BN / 64;         // loads per stage: 4 or 3

  // staging: thread t -> LDS row t>>2, chunk t&3; global k-chunk is XOR-swizzled
  const int srow = t >> 2;
  const int sk8 = ((t & 3) ^ ((srow >> 1) & 3)) * 8;
  // swizzled chunk offset for fragment reads (row-bits come only from lr)
  const int ck = ((lk ^ ((lr >> 1) & 3)) << 3);

  const size_t aOff0 = (size_t)(ti * 128 + srow) * lda + sk8;
  const size_t aOff1 = (size_t)(ti * 128 + 64 + srow) * lda + sk8;
  const size_t bOff0 = (size_t)(tj * BN + srow) * ldb + sk8;
  const size_t bOff1 = (size_t)(tj * BN + 64 + srow) * ldb + sk8;  // BN=128 only

  const int Keff = KROW ? (ti + 1) * 128 : K;
  const int nsteps = Keff >> 5;

  auto stage = [&](int bu, int kk) {
    const int kb = kk * 32;
    GLL16(pA + aOff0 + kb, As + bu * 4096 + w * 512);
    GLL16(pA + aOff1 + kb, As + bu * 4096 + 2048 + w * 512);
    GLL16(pB + bOff0 + kb, Bs + bu * BSZ + w * 512);
    if constexpr (BN == 128) GLL16(pB + bOff1 + kb, Bs + bu * BSZ + 2048 + w * 512);
  };

  f32x4 acc[4][NI] = {};

  stage(0, 0);
  int buf = 0;
  for (int kk = 0; kk < nsteps; ++kk) {
    if (kk + 1 < nsteps) {
      stage(buf ^ 1, kk + 1);  // next-tile loads fly across the barriers
      if constexpr (LPS == 4) asm volatile("s_waitcnt vmcnt(4)" ::: "memory");
      else                    asm volatile("s_waitcnt vmcnt(3)" ::: "memory");
    } else {
      asm volatile("s_waitcnt vmcnt(0)" ::: "memory");
    }
    BARRIER();  // all waves' tile-k loads landed

    f16x8 ah[4], bh[NI];
#pragma unroll
    for (int mi = 0; mi < 4; ++mi) {
      const int ae = buf * 4096 + (wr * 64 + mi * 16 + lr) * 32 + ck;
      ah[mi] = *(const f16x8*)&As[ae];
    }
#pragma unroll
    for (int ni = 0; ni < NI; ++ni) {
      const int be = buf * BSZ + (wc * (BN / 2) + ni * 16 + lr) * 32 + ck;
      bh[ni] = *(const f16x8*)&Bs[be];
    }
#pragma unroll
    for (int mi = 0; mi < 4; ++mi)
#pragma unroll
      for (int ni = 0; ni < NI; ++ni)
        acc[mi][ni] = __builtin_amdgcn_mfma_f32_16x16x32_f16(ah[mi], bh[ni], acc[mi][ni], 0, 0, 0);
    BARRIER();  // all waves done reading buf before next stage overwrites it
    buf ^= 1;
  }

  // epilogue: C/D layout col = lane&15, row = (lane>>4)*4 + reg  [m89-verified]
#pragma unroll
  for (int mi = 0; mi < 4; ++mi)
#pragma unroll
    for (int ni = 0; ni < NI; ++ni)
#pragma unroll
      for (int r = 0; r < 4; ++r) {
        const int row = ti * 128 + wr * 64 + mi * 16 + lk * 4 + r;
        const int col = tj * BN + wc * (BN / 2) + ni * 16 + lr;
        float v = acc[mi][ni][r];
        if (CAUSAL && col > row) v = -1e30f;
        const size_t idx = cbase + (size_t)row * ldc + col;
        if (EPI == 0) ((float*)Cv)[idx] = v;
        else          ((u16*)Cv)[idx] = f2h(v);
      }
}

// ---------------- generic GEMM wrapper (XCD-chunk bijective remap, m204) ----
template <int EPI, int CAUSAL, int KROW, int BN>
__global__ __launch_bounds__(256, 4) void gemm_k(
    const u16* __restrict__ A, long sAb, const u16* __restrict__ B, long sBb,
    void* __restrict__ Cv, long sCb,
    int K, int lda, int ldb, int ldc, int gx, int gy) {
  __shared__ __align__(16) u16 lds[2 * (4096 + BN * 32)];
  const int nwg = gridDim.x;
  const int orig = blockIdx.x;
  const int q8 = nwg >> 3, r8 = nwg & 7;
  const int xcd = orig & 7, pos = orig >> 3;
  const int wgid = (xcd < r8 ? xcd * (q8 + 1) : r8 * (q8 + 1) + (xcd - r8) * q8) + pos;
  const int tj = wgid % gx;
  const int rest = wgid / gx;
  const int ti = rest % gy;
  const int zb = rest / gy;
  if (CAUSAL && tj > ti) return;
  gemm_body<EPI, CAUSAL, KROW, BN>(
      lds, A + (size_t)zb * sAb, B + (size_t)zb * sBb,
      Cv, (size_t)zb * sCb, K, lda, ldb, ldc, ti, tj);
}

// ---------------- fused projection: q' + vt (both 1-pass fp16 now) ----------
// 1536 equal-cost blocks. Per x-row-tile sidx: sub 0..5 = q' col-tiles,
// sub 6..11 = vt row-tiles (share the same x tiles -> L2 reuse per XCD chunk).
__global__ __launch_bounds__(256, 4) void proj_kernel(
    const u16* __restrict__ xf, const u16* __restrict__ mt16,
    const u16* __restrict__ wvt16,
    u16* __restrict__ qf, u16* __restrict__ vtf) {
  __shared__ __align__(16) u16 lds[2 * (4096 + 4096)];
  const int orig = blockIdx.x;
  const int wgid = (orig & 7) * 192 + (orig >> 3);  // bijective (1536 % 8 == 0)
  const int sidx = wgid / 12, sub = wgid % 12;
  if (sub < 6) {
    // q'[s][j] = sum_d x[s][d] * Mt[j][d]  (fp16 out)
    gemm_body<2, 0, 0, 128>(lds, xf, mt16, qf, 0, 768, 768, 768, 768, sidx, sub);
  } else {
    // vt[h][s] = sum_d WvT[h][d] * x[s][d]  (fp16 out)
    gemm_body<2, 0, 0, 128>(lds, wvt16, xf, vtf, 0, 768, 768, 768, 16384, sub - 6, sidx);
  }
}

// ---------------- causal row softmax: scores f32 -> P fp16 ----------------
__global__ __launch_bounds__(256) void softmax_kernel(const float* __restrict__ S,
                                                      u16* __restrict__ P,
                                                      long sSb, long sPb) {
  const int wid = blockIdx.x * 4 + (threadIdx.x >> 6);  // one wave per row
  const int l = threadIdx.x & 63;
  const int zb = wid >> 11;
  const int i = wid & 2047;
  const float* row = S + (size_t)zb * sSb + (size_t)i * 2048;
  u16* prow = P + (size_t)zb * sPb + (size_t)i * 2048;
  const int Tend = ((i >> 7) + 1) << 7;  // multiple of 128
  const int nch = (Tend + 255) >> 8;

  f32x4 vb[8];
  float mx = -3e38f;
  for (int c = 0; c < nch; ++c) {
    const int j = c * 256 + l * 4;
    f32x4 v;
    if (j < Tend) v = *(const f32x4*)(row + j);
    else { v[0] = v[1] = v[2] = v[3] = -3e38f; }
    vb[c] = v;
    mx = fmaxf(mx, fmaxf(fmaxf(v[0], v[1]), fmaxf(v[2], v[3])));
  }
#pragma unroll
  for (int s = 32; s; s >>= 1) mx = fmaxf(mx, __shfl_xor(mx, s));

  float sum = 0.f;
  for (int c = 0; c < nch; ++c) {
    f32x4 v = vb[c];
#pragma unroll
    for (int j = 0; j < 4; ++j) {
      float e = expf(v[j] - mx);  // -1e30/-3e38 -> 0
      v[j] = e;
      sum += e;
    }
    vb[c] = v;
  }
#pragma unroll
  for (int s = 32; s; s >>= 1) sum += __shfl_xor(sum, s);
  const float inv = 1.f / sum;

  for (int c = 0; c < nch; ++c) {
    const int j = c * 256 + l * 4;
    if (j < Tend) {
      f32x4 v = vb[c];
      u16x4 o;
#pragma unroll
      for (int q = 0; q < 4; ++q) o[q] = f2h(v[q] * inv);
      *(u16x4*)(prow + j) = o;
    }
  }
}

// ---------------- orchestration ----------------
extern "C" void kernel_launch(void* const* d_in, const int* in_sizes, int n_in,
                              void* d_out, int out_size, void* d_ws, size_t ws_size,
                              hipStream_t stream) {
  const float* x  = (const float*)d_in[0];
  const float* Wq = (const float*)d_in[1];
  const float* Wk = (const float*)d_in[2];
  const float* Wv = (const float*)d_in[3];
  float* out = (float*)d_out;

  const int S = 2048, D = 768;
  const size_t ND = (size_t)8 * S * D;        // 12.58M
  const size_t NW = (size_t)D * D;            // 589824

  char* ws = (char*)d_ws;
  size_t off = 0;
  auto alloc = [&](size_t bytes) { size_t o = off; off = (off + bytes + 255) & ~(size_t)255; return o; };

  u16* xf   = (u16*)(ws + alloc(ND * 2));
  u16* qf   = (u16*)(ws + alloc(ND * 2));
  u16* vtf  = (u16*)(ws + alloc(ND * 2));
  u16* wq16 = (u16*)(ws + alloc(NW * 2));
  u16* wk16 = (u16*)(ws + alloc(NW * 2));
  u16* wvt16= (u16*)(ws + alloc(NW * 2));
  u16* mt16 = (u16*)(ws + alloc(NW * 2));
  const size_t fixed = off;

  const size_t perBatch = (size_t)S * S * 4 + (size_t)S * S * 2 + 512;  // scores f32 + P fp16
  int g = 0;
  for (int cand = 8; cand >= 1; cand >>= 1)
    if (fixed + (size_t)cand * perBatch <= ws_size) { g = cand; break; }
  if (!g) return;

  float* sc = (float*)(ws + alloc((size_t)g * S * S * 4));
  u16*   P  = (u16*)(ws + alloc((size_t)g * S * S * 2));

  // fused prep: fp16 casts + Wv transpose
  prep_kernel<<<15744, 256, 0, stream>>>(x, Wq, Wk, Wv, xf, wq16, wk16, wvt16);

  // Mt[e][d] = sum_h Wk[e][h] * Wq[d][h]   (= (Wq Wk^T)^T), fp16 out, BN=64
  gemm_k<2, 0, 0, 64><<<72, 256, 0, stream>>>(
      wk16, 0, wq16, 0, mt16, 0, 768, 768, 768, 768, 12, 6);

  // fused q' + vt (1536 equal-cost blocks)
  proj_kernel<<<1536, 256, 0, stream>>>(xf, mt16, wvt16, qf, vtf);

  for (int b0 = 0; b0 < 8; b0 += g) {
    // scores[b][i][j] = q'[b,i] . x[b,j]  (causal tiles only, mask to -1e30)
    gemm_k<0, 1, 0, 128><<<16 * 16 * g, 256, 0, stream>>>(
        qf + (size_t)b0 * S * D, (long)S * D,
        xf + (size_t)b0 * S * D, (long)S * D,
        sc, (long)S * S, 768, 768, 768, 2048, 16, 16);

    softmax_kernel<<<g * 512, 256, 0, stream>>>(sc, P, (long)S * S, (long)S * S);

    // out[b][i][h] = sum_{j<Tend} P[b][i][j] * vt[h][b*2048+j]  (BN=64)
    gemm_k<0, 0, 1, 64><<<12 * 16 * g, 256, 0, stream>>>(
        P, (long)S * S,
        vtf + (size_t)b0 * S, (long)S,
        out + (size_t)b0 * S * D, (long)S * D,
        2048, 2048, 16384, 768, 12, 16);
  }
}

// Round 9
// 227.890 us; speedup vs baseline: 1.8042x; 1.0531x over previous
//
#include <hip/hip_runtime.h>

typedef unsigned short u16;
typedef _Float16 f16;
typedef float  f32x4  __attribute__((ext_vector_type(4)));
typedef unsigned short u16x4 __attribute__((ext_vector_type(4)));
typedef f16    f16x8  __attribute__((ext_vector_type(8)));

__device__ __forceinline__ u16 f2h(float f) {
  f16 h = (f16)f;                      // RTN-even via v_cvt_f16_f32
  return __builtin_bit_cast(u16, h);
}

// raw s_barrier with compiler memory fences (no vmcnt drain)
#define BARRIER()                          \
  do {                                     \
    asm volatile("" ::: "memory");         \
    __builtin_amdgcn_s_barrier();          \
    asm volatile("" ::: "memory");         \
  } while (0)

#define GLL16(g, l)                                                              \
  __builtin_amdgcn_global_load_lds(                                              \
      (const __attribute__((address_space(1))) unsigned int*)(g),                \
      (__attribute__((address_space(3))) unsigned int*)(l), 16, 0, 0)

// ---------------- fused prep: fp16 casts of x/Wq/Wk + transposed Wv ----------
__global__ __launch_bounds__(256) void prep_kernel(
    const float* __restrict__ x, const float* __restrict__ Wq,
    const float* __restrict__ Wk, const float* __restrict__ Wv,
    u16* __restrict__ xf, u16* __restrict__ wq16,
    u16* __restrict__ wk16, u16* __restrict__ wvt16) {
  const int bid = blockIdx.x, tid = threadIdx.x;
  if (bid < 13440) {  // straight f32 -> fp16 casts, vectorized
    const float* src;
    u16* dst;
    int i;
    if (bid < 12288) { src = x;  dst = xf;   i = bid * 256 + tid; }
    else if (bid < 12864) { src = Wq; dst = wq16; i = (bid - 12288) * 256 + tid; }
    else { src = Wk; dst = wk16; i = (bid - 12864) * 256 + tid; }
    f32x4 v = ((const f32x4*)src)[i];
    u16x4 h;
#pragma unroll
    for (int j = 0; j < 4; ++j) h[j] = f2h(v[j]);
    ((u16x4*)dst)[i] = h;
  } else {  // Wv transpose: 2304 blocks, 589824 elems
    int i = (bid - 13440) * 256 + tid;
    int h = i / 768, d = i % 768;
    wvt16[i] = f2h(Wv[d * 768 + h]);
  }
}

// ---------------- GEMM body: C(128 x BN) = A * B^T  (fp16 MFMA) -------------
// BK=32, 4 waves (2x2; wave = 64 x BN/2), 16x16x32 f16 MFMA.
// T4 counted-vmcnt double-buffer; raw barriers (loads stay in flight).
// Bank swizzle: LDS chunk c of row r holds global k-chunk c ^ ((r>>1)&3).
// EPI: 0 = f32 store (+causal mask), 2 = fp16 store
// LDS layout: As [2][4096] u16, then Bs [2][BN*32] u16.
template <int EPI, int CAUSAL, int KROW, int BN>
__device__ __forceinline__ void gemm_body(
    u16* __restrict__ lds,
    const u16* __restrict__ pA, const u16* __restrict__ pB,
    void* __restrict__ Cv, size_t cbase,
    int K, int lda, int ldb, int ldc, int ti, int tj) {
  constexpr int BSZ = BN * 32;
  u16* As = lds;                 // [2][4096]
  u16* Bs = lds + 2 * 4096;      // [2][BSZ]

  const int t = threadIdx.x, w = t >> 6, l = t & 63;
  const int wr = w >> 1, wc = w & 1;
  const int lr = l & 15, lk = l >> 4;
  constexpr int NI = BN / 32;              // 4 (BN=128) or 2 (BN=64)
  constexpr int LPS = 2 + BN / 64;         // loads per stage: 4 or 3

  // staging: thread t -> LDS row t>>2, chunk t&3; global k-chunk is XOR-swizzled
  const int srow = t >> 2;
  const int sk8 = ((t & 3) ^ ((srow >> 1) & 3)) * 8;
  // swizzled chunk offset for fragment reads (row-bits come only from lr)
  const int ck = ((lk ^ ((lr >> 1) & 3)) << 3);

  const size_t aOff0 = (size_t)(ti * 128 + srow) * lda + sk8;
  const size_t aOff1 = (size_t)(ti * 128 + 64 + srow) * lda + sk8;
  const size_t bOff0 = (size_t)(tj * BN + srow) * ldb + sk8;
  const size_t bOff1 = (size_t)(tj * BN + 64 + srow) * ldb + sk8;  // BN=128 only

  const int Keff = KROW ? (ti + 1) * 128 : K;
  const int nsteps = Keff >> 5;

  auto stage = [&](int bu, int kk) {
    const int kb = kk * 32;
    GLL16(pA + aOff0 + kb, As + bu * 4096 + w * 512);
    GLL16(pA + aOff1 + kb, As + bu * 4096 + 2048 + w * 512);
    GLL16(pB + bOff0 + kb, Bs + bu * BSZ + w * 512);
    if constexpr (BN == 128) GLL16(pB + bOff1 + kb, Bs + bu * BSZ + 2048 + w * 512);
  };

  f32x4 acc[4][NI] = {};

  stage(0, 0);
  int buf = 0;
  for (int kk = 0; kk < nsteps; ++kk) {
    if (kk + 1 < nsteps) {
      stage(buf ^ 1, kk + 1);  // next-tile loads fly across the barriers
      if constexpr (LPS == 4) asm volatile("s_waitcnt vmcnt(4)" ::: "memory");
      else                    asm volatile("s_waitcnt vmcnt(3)" ::: "memory");
    } else {
      asm volatile("s_waitcnt vmcnt(0)" ::: "memory");
    }
    BARRIER();  // all waves' tile-k loads landed

    f16x8 ah[4], bh[NI];
#pragma unroll
    for (int mi = 0; mi < 4; ++mi) {
      const int ae = buf * 4096 + (wr * 64 + mi * 16 + lr) * 32 + ck;
      ah[mi] = *(const f16x8*)&As[ae];
    }
#pragma unroll
    for (int ni = 0; ni < NI; ++ni) {
      const int be = buf * BSZ + (wc * (BN / 2) + ni * 16 + lr) * 32 + ck;
      bh[ni] = *(const f16x8*)&Bs[be];
    }
#pragma unroll
    for (int mi = 0; mi < 4; ++mi)
#pragma unroll
      for (int ni = 0; ni < NI; ++ni)
        acc[mi][ni] = __builtin_amdgcn_mfma_f32_16x16x32_f16(ah[mi], bh[ni], acc[mi][ni], 0, 0, 0);
    BARRIER();  // all waves done reading buf before next stage overwrites it
    buf ^= 1;
  }

  // epilogue: C/D layout col = lane&15, row = (lane>>4)*4 + reg  [m89-verified]
#pragma unroll
  for (int mi = 0; mi < 4; ++mi)
#pragma unroll
    for (int ni = 0; ni < NI; ++ni)
#pragma unroll
      for (int r = 0; r < 4; ++r) {
        const int row = ti * 128 + wr * 64 + mi * 16 + lk * 4 + r;
        const int col = tj * BN + wc * (BN / 2) + ni * 16 + lr;
        float v = acc[mi][ni][r];
        if (CAUSAL && col > row) v = -1e30f;
        const size_t idx = cbase + (size_t)row * ldc + col;
        if (EPI == 0) ((float*)Cv)[idx] = v;
        else          ((u16*)Cv)[idx] = f2h(v);
      }
}

// ---------------- generic GEMM wrapper (XCD-chunk bijective remap, m204) ----
template <int EPI, int CAUSAL, int KROW, int BN>
__global__ __launch_bounds__(256, 4) void gemm_k(
    const u16* __restrict__ A, long sAb, const u16* __restrict__ B, long sBb,
    void* __restrict__ Cv, long sCb,
    int K, int lda, int ldb, int ldc, int gx, int gy) {
  __shared__ __align__(16) u16 lds[2 * (4096 + BN * 32)];
  const int nwg = gridDim.x;
  const int orig = blockIdx.x;
  const int q8 = nwg >> 3, r8 = nwg & 7;
  const int xcd = orig & 7, pos = orig >> 3;
  const int wgid = (xcd < r8 ? xcd * (q8 + 1) : r8 * (q8 + 1) + (xcd - r8) * q8) + pos;
  const int tj = wgid % gx;
  const int rest = wgid / gx;
  const int ti = rest % gy;
  const int zb = rest / gy;
  if (CAUSAL && tj > ti) return;
  gemm_body<EPI, CAUSAL, KROW, BN>(
      lds, A + (size_t)zb * sAb, B + (size_t)zb * sBb,
      Cv, (size_t)zb * sCb, K, lda, ldb, ldc, ti, tj);
}

// ---------------- fused projection: q' + vt, 768 all-resident blocks --------
// 2 jobs per block (1536 jobs): zero generation-tail (768 blocks all fit at
// >=3/CU). Consecutive jobs share the same x row-tile -> L2 reuse.
// Per x-row-tile sidx: sub 0..5 = q' col-tiles, sub 6..11 = vt row-tiles.
__global__ __launch_bounds__(256, 4) void proj_kernel(
    const u16* __restrict__ xf, const u16* __restrict__ mt16,
    const u16* __restrict__ wvt16,
    u16* __restrict__ qf, u16* __restrict__ vtf) {
  __shared__ __align__(16) u16 lds[2 * (4096 + 4096)];
  const int orig = blockIdx.x;
  const int wgid = (orig & 7) * 96 + (orig >> 3);  // bijective (768 % 8 == 0)
#pragma unroll
  for (int j = 0; j < 2; ++j) {
    const int job = wgid * 2 + j;
    const int sidx = job / 12, sub = job % 12;
    if (sub < 6) {
      // q'[s][j] = sum_d x[s][d] * Mt[j][d]  (fp16 out)
      gemm_body<2, 0, 0, 128>(lds, xf, mt16, qf, 0, 768, 768, 768, 768, sidx, sub);
    } else {
      // vt[h][s] = sum_d WvT[h][d] * x[s][d]  (fp16 out)
      gemm_body<2, 0, 0, 128>(lds, wvt16, xf, vtf, 0, 768, 768, 768, 16384, sub - 6, sidx);
    }
    // no barrier needed between jobs: job j+1's first consumer BARRIER covers
    // its own staging, and epilogue touches only global memory.
  }
}

// ---------------- causal row softmax: scores f32 -> P fp16 ----------------
__global__ __launch_bounds__(256) void softmax_kernel(const float* __restrict__ S,
                                                      u16* __restrict__ P,
                                                      long sSb, long sPb) {
  const int wid = blockIdx.x * 4 + (threadIdx.x >> 6);  // one wave per row
  const int l = threadIdx.x & 63;
  const int zb = wid >> 11;
  const int i = wid & 2047;
  const float* row = S + (size_t)zb * sSb + (size_t)i * 2048;
  u16* prow = P + (size_t)zb * sPb + (size_t)i * 2048;
  const int Tend = ((i >> 7) + 1) << 7;  // multiple of 128
  const int nch = (Tend + 255) >> 8;

  f32x4 vb[8];
  float mx = -3e38f;
  for (int c = 0; c < nch; ++c) {
    const int j = c * 256 + l * 4;
    f32x4 v;
    if (j < Tend) v = *(const f32x4*)(row + j);
    else { v[0] = v[1] = v[2] = v[3] = -3e38f; }
    vb[c] = v;
    mx = fmaxf(mx, fmaxf(fmaxf(v[0], v[1]), fmaxf(v[2], v[3])));
  }
#pragma unroll
  for (int s = 32; s; s >>= 1) mx = fmaxf(mx, __shfl_xor(mx, s));

  float sum = 0.f;
  for (int c = 0; c < nch; ++c) {
    f32x4 v = vb[c];
#pragma unroll
    for (int j = 0; j < 4; ++j) {
      float e = expf(v[j] - mx);  // -1e30/-3e38 -> 0
      v[j] = e;
      sum += e;
    }
    vb[c] = v;
  }
#pragma unroll
  for (int s = 32; s; s >>= 1) sum += __shfl_xor(sum, s);
  const float inv = 1.f / sum;

  for (int c = 0; c < nch; ++c) {
    const int j = c * 256 + l * 4;
    if (j < Tend) {
      f32x4 v = vb[c];
      u16x4 o;
#pragma unroll
      for (int q = 0; q < 4; ++q) o[q] = f2h(v[q] * inv);
      *(u16x4*)(prow + j) = o;
    }
  }
}

// ---------------- orchestration ----------------
extern "C" void kernel_launch(void* const* d_in, const int* in_sizes, int n_in,
                              void* d_out, int out_size, void* d_ws, size_t ws_size,
                              hipStream_t stream) {
  const float* x  = (const float*)d_in[0];
  const float* Wq = (const float*)d_in[1];
  const float* Wk = (const float*)d_in[2];
  const float* Wv = (const float*)d_in[3];
  float* out = (float*)d_out;

  const int S = 2048, D = 768;
  const size_t ND = (size_t)8 * S * D;        // 12.58M
  const size_t NW = (size_t)D * D;            // 589824

  char* ws = (char*)d_ws;
  size_t off = 0;
  auto alloc = [&](size_t bytes) { size_t o = off; off = (off + bytes + 255) & ~(size_t)255; return o; };

  u16* xf   = (u16*)(ws + alloc(ND * 2));
  u16* qf   = (u16*)(ws + alloc(ND * 2));
  u16* vtf  = (u16*)(ws + alloc(ND * 2));
  u16* wq16 = (u16*)(ws + alloc(NW * 2));
  u16* wk16 = (u16*)(ws + alloc(NW * 2));
  u16* wvt16= (u16*)(ws + alloc(NW * 2));
  u16* mt16 = (u16*)(ws + alloc(NW * 2));
  const size_t fixed = off;

  const size_t perBatch = (size_t)S * S * 4 + (size_t)S * S * 2 + 512;  // scores f32 + P fp16
  int g = 0;
  for (int cand = 8; cand >= 1; cand >>= 1)
    if (fixed + (size_t)cand * perBatch <= ws_size) { g = cand; break; }
  if (!g) return;

  float* sc = (float*)(ws + alloc((size_t)g * S * S * 4));
  u16*   P  = (u16*)(ws + alloc((size_t)g * S * S * 2));

  // fused prep: fp16 casts + Wv transpose
  prep_kernel<<<15744, 256, 0, stream>>>(x, Wq, Wk, Wv, xf, wq16, wk16, wvt16);

  // Mt[e][d] = sum_h Wk[e][h] * Wq[d][h]   (= (Wq Wk^T)^T), fp16 out, BN=64
  gemm_k<2, 0, 0, 64><<<72, 256, 0, stream>>>(
      wk16, 0, wq16, 0, mt16, 0, 768, 768, 768, 768, 12, 6);

  // fused q' + vt: 768 all-resident blocks x 2 jobs
  proj_kernel<<<768, 256, 0, stream>>>(xf, mt16, wvt16, qf, vtf);

  for (int b0 = 0; b0 < 8; b0 += g) {
    // scores[b][i][j] = q'[b,i] . x[b,j]  (causal tiles only, mask to -1e30)
    gemm_k<0, 1, 0, 128><<<16 * 16 * g, 256, 0, stream>>>(
        qf + (size_t)b0 * S * D, (long)S * D,
        xf + (size_t)b0 * S * D, (long)S * D,
        sc, (long)S * S, 768, 768, 768, 2048, 16, 16);

    softmax_kernel<<<g * 512, 256, 0, stream>>>(sc, P, (long)S * S, (long)S * S);

    // out[b][i][h] = sum_{j<Tend} P[b][i][j] * vt[h][b*2048+j]  (BN=128, all-resident)
    gemm_k<0, 0, 1, 128><<<6 * 16 * g, 256, 0, stream>>>(
        P, (long)S * S,
        vtf + (size_t)b0 * S, (long)S,
        out + (size_t)b0 * S * D, (long)S * D,
        2048, 2048, 16384, 768, 6, 16);
  }
}

// Round 11
// 227.672 us; speedup vs baseline: 1.8060x; 1.0010x over previous
//
#include <hip/hip_runtime.h>

typedef unsigned short u16;
typedef _Float16 f16;
typedef float  f32x4  __attribute__((ext_vector_type(4)));
typedef unsigned short u16x4 __attribute__((ext_vector_type(4)));
typedef f16    f16x8  __attribute__((ext_vector_type(8)));

__device__ __forceinline__ u16 f2h(float f) {
  f16 h = (f16)f;                      // RTN-even via v_cvt_f16_f32
  return __builtin_bit_cast(u16, h);
}

// raw s_barrier with compiler memory fences (no vmcnt drain)
#define BARRIER()                          \
  do {                                     \
    asm volatile("" ::: "memory");         \
    __builtin_amdgcn_s_barrier();          \
    asm volatile("" ::: "memory");         \
  } while (0)

#define GLL16(g, l)                                                              \
  __builtin_amdgcn_global_load_lds(                                              \
      (const __attribute__((address_space(1))) unsigned int*)(g),                \
      (__attribute__((address_space(3))) unsigned int*)(l), 16, 0, 0)

// ---------------- fused prep: fp16 casts of x/Wq/Wk + transposed Wv ----------
__global__ __launch_bounds__(256) void prep_kernel(
    const float* __restrict__ x, const float* __restrict__ Wq,
    const float* __restrict__ Wk, const float* __restrict__ Wv,
    u16* __restrict__ xf, u16* __restrict__ wq16,
    u16* __restrict__ wk16, u16* __restrict__ wvt16) {
  const int bid = blockIdx.x, tid = threadIdx.x;
  if (bid < 13440) {  // straight f32 -> fp16 casts, vectorized
    const float* src;
    u16* dst;
    int i;
    if (bid < 12288) { src = x;  dst = xf;   i = bid * 256 + tid; }
    else if (bid < 12864) { src = Wq; dst = wq16; i = (bid - 12288) * 256 + tid; }
    else { src = Wk; dst = wk16; i = (bid - 12864) * 256 + tid; }
    f32x4 v = ((const f32x4*)src)[i];
    u16x4 h;
#pragma unroll
    for (int j = 0; j < 4; ++j) h[j] = f2h(v[j]);
    ((u16x4*)dst)[i] = h;
  } else {  // Wv transpose: 2304 blocks, 589824 elems
    int i = (bid - 13440) * 256 + tid;
    int h = i / 768, d = i % 768;
    wvt16[i] = f2h(Wv[d * 768 + h]);
  }
}

// ---------------- GEMM body: C(128 x BN) = A * B^T  (fp16 MFMA) -------------
// BK=32, 4 waves (2x2; wave = 64 x BN/2), 16x16x32 f16 MFMA.
// DEPTH-deep counted-vmcnt pipeline (2 or 3): stage k+DEPTH-1 each step,
// wait vmcnt((DEPTH-1)*LPS) -> each load gets DEPTH-1 K-steps to land.
// Raw barriers; loads stay in flight across them.
// Bank swizzle: LDS chunk c of row r holds global k-chunk c ^ ((r>>1)&3).
// EPI: 0 = f32 store (+causal mask), 2 = fp16 store
// LDS layout: As [DEPTH][4096] u16, then Bs [DEPTH][BN*32] u16.
template <int EPI, int CAUSAL, int KROW, int BN, int DEPTH>
__device__ __forceinline__ void gemm_body(
    u16* __restrict__ lds,
    const u16* __restrict__ pA, const u16* __restrict__ pB,
    void* __restrict__ Cv, size_t cbase,
    int K, int lda, int ldb, int ldc, int ti, int tj) {
  constexpr int BSZ = BN * 32;
  u16* As = lds;                     // [DEPTH][4096]
  u16* Bs = lds + DEPTH * 4096;      // [DEPTH][BSZ]

  const int t = threadIdx.x, w = t >> 6, l = t & 63;
  const int wr = w >> 1, wc = w & 1;
  const int lr = l & 15, lk = l >> 4;
  constexpr int NI = BN / 32;              // 4 (BN=128) or 2 (BN=64)
  constexpr int LPS = 2 + BN / 64;         // loads per stage: 4 or 3

  // staging: thread t -> LDS row t>>2, chunk t&3; global k-chunk is XOR-swizzled
  const int srow = t >> 2;
  const int sk8 = ((t & 3) ^ ((srow >> 1) & 3)) * 8;
  // swizzled chunk offset for fragment reads (row-bits come only from lr)
  const int ck = ((lk ^ ((lr >> 1) & 3)) << 3);

  const size_t aOff0 = (size_t)(ti * 128 + srow) * lda + sk8;
  const size_t aOff1 = (size_t)(ti * 128 + 64 + srow) * lda + sk8;
  const size_t bOff0 = (size_t)(tj * BN + srow) * ldb + sk8;
  const size_t bOff1 = (size_t)(tj * BN + 64 + srow) * ldb + sk8;  // BN=128 only

  const int Keff = KROW ? (ti + 1) * 128 : K;
  const int nsteps = Keff >> 5;

  auto stage = [&](int bu, int kk) {
    const int kb = kk * 32;
    GLL16(pA + aOff0 + kb, As + bu * 4096 + w * 512);
    GLL16(pA + aOff1 + kb, As + bu * 4096 + 2048 + w * 512);
    GLL16(pB + bOff0 + kb, Bs + bu * BSZ + w * 512);
    if constexpr (BN == 128) GLL16(pB + bOff1 + kb, Bs + bu * BSZ + 2048 + w * 512);
  };

  f32x4 acc[4][NI] = {};

  stage(0, 0);
  if constexpr (DEPTH == 3) { if (nsteps > 1) stage(1, 1); }
  for (int kk = 0; kk < nsteps; ++kk) {
    const int buf = kk % DEPTH;
    if constexpr (DEPTH == 2) {
      if (kk + 1 < nsteps) {
        stage((kk + 1) % 2, kk + 1);
        if constexpr (LPS == 4) asm volatile("s_waitcnt vmcnt(4)" ::: "memory");
        else                    asm volatile("s_waitcnt vmcnt(3)" ::: "memory");
      } else {
        asm volatile("s_waitcnt vmcnt(0)" ::: "memory");
      }
    } else {
      if (kk + 2 < nsteps) {
        stage((kk + 2) % 3, kk + 2);
        if constexpr (LPS == 4) asm volatile("s_waitcnt vmcnt(8)" ::: "memory");
        else                    asm volatile("s_waitcnt vmcnt(6)" ::: "memory");
      } else if (kk + 1 < nsteps) {
        if constexpr (LPS == 4) asm volatile("s_waitcnt vmcnt(4)" ::: "memory");
        else                    asm volatile("s_waitcnt vmcnt(3)" ::: "memory");
      } else {
        asm volatile("s_waitcnt vmcnt(0)" ::: "memory");
      }
    }
    BARRIER();  // all waves' tile-k loads landed

    f16x8 ah[4], bh[NI];
#pragma unroll
    for (int mi = 0; mi < 4; ++mi) {
      const int ae = buf * 4096 + (wr * 64 + mi * 16 + lr) * 32 + ck;
      ah[mi] = *(const f16x8*)&As[ae];
    }
#pragma unroll
    for (int ni = 0; ni < NI; ++ni) {
      const int be = buf * BSZ + (wc * (BN / 2) + ni * 16 + lr) * 32 + ck;
      bh[ni] = *(const f16x8*)&Bs[be];
    }
#pragma unroll
    for (int mi = 0; mi < 4; ++mi)
#pragma unroll
      for (int ni = 0; ni < NI; ++ni)
        acc[mi][ni] = __builtin_amdgcn_mfma_f32_16x16x32_f16(ah[mi], bh[ni], acc[mi][ni], 0, 0, 0);
    BARRIER();  // all waves done reading buf before its next overwrite issues
  }

  // epilogue: C/D layout col = lane&15, row = (lane>>4)*4 + reg  [m89-verified]
#pragma unroll
  for (int mi = 0; mi < 4; ++mi)
#pragma unroll
    for (int ni = 0; ni < NI; ++ni)
#pragma unroll
      for (int r = 0; r < 4; ++r) {
        const int row = ti * 128 + wr * 64 + mi * 16 + lk * 4 + r;
        const int col = tj * BN + wc * (BN / 2) + ni * 16 + lr;
        float v = acc[mi][ni][r];
        if (CAUSAL && col > row) v = -1e30f;
        const size_t idx = cbase + (size_t)row * ldc + col;
        if (EPI == 0) ((float*)Cv)[idx] = v;
        else          ((u16*)Cv)[idx] = f2h(v);
      }
}

// ---------------- generic GEMM wrapper (XCD-chunk bijective remap, m204) ----
template <int EPI, int CAUSAL, int KROW, int BN, int DEPTH>
__global__ __launch_bounds__(256, (DEPTH == 3) ? 3 : 4) void gemm_k(
    const u16* __restrict__ A, long sAb, const u16* __restrict__ B, long sBb,
    void* __restrict__ Cv, long sCb,
    int K, int lda, int ldb, int ldc, int gx, int gy) {
  __shared__ __align__(16) u16 lds[DEPTH * (4096 + BN * 32)];
  const int nwg = gridDim.x;
  const int orig = blockIdx.x;
  const int q8 = nwg >> 3, r8 = nwg & 7;
  const int xcd = orig & 7, pos = orig >> 3;
  const int wgid = (xcd < r8 ? xcd * (q8 + 1) : r8 * (q8 + 1) + (xcd - r8) * q8) + pos;
  const int tj = wgid % gx;
  const int rest = wgid / gx;
  const int ti = rest % gy;
  const int zb = rest / gy;
  if (CAUSAL && tj > ti) return;
  gemm_body<EPI, CAUSAL, KROW, BN, DEPTH>(
      lds, A + (size_t)zb * sAb, B + (size_t)zb * sBb,
      Cv, (size_t)zb * sCb, K, lda, ldb, ldc, ti, tj);
}

// ---------------- fused projection: q' + vt, 768 all-resident blocks --------
// 2 jobs per block (1536 jobs), DEPTH=3 pipeline (48KB LDS, 3/CU, all resident).
// Per x-row-tile sidx: sub 0..5 = q' col-tiles, sub 6..11 = vt row-tiles.
__global__ __launch_bounds__(256, 3) void proj_kernel(
    const u16* __restrict__ xf, const u16* __restrict__ mt16,
    const u16* __restrict__ wvt16,
    u16* __restrict__ qf, u16* __restrict__ vtf) {
  __shared__ __align__(16) u16 lds[3 * (4096 + 4096)];
  const int orig = blockIdx.x;
  const int wgid = (orig & 7) * 96 + (orig >> 3);  // bijective (768 % 8 == 0)
#pragma unroll
  for (int j = 0; j < 2; ++j) {
    const int job = wgid * 2 + j;
    const int sidx = job / 12, sub = job % 12;
    if (sub < 6) {
      // q'[s][j] = sum_d x[s][d] * Mt[j][d]  (fp16 out)
      gemm_body<2, 0, 0, 128, 3>(lds, xf, mt16, qf, 0, 768, 768, 768, 768, sidx, sub);
    } else {
      // vt[h][s] = sum_d WvT[h][d] * x[s][d]  (fp16 out)
      gemm_body<2, 0, 0, 128, 3>(lds, wvt16, xf, vtf, 0, 768, 768, 768, 16384, sub - 6, sidx);
    }
  }
}

// ---------------- causal row softmax: scores f32 -> P fp16 ----------------
__global__ __launch_bounds__(256) void softmax_kernel(const float* __restrict__ S,
                                                      u16* __restrict__ P,
                                                      long sSb, long sPb) {
  const int wid = blockIdx.x * 4 + (threadIdx.x >> 6);  // one wave per row
  const int l = threadIdx.x & 63;
  const int zb = wid >> 11;
  const int i = wid & 2047;
  const float* row = S + (size_t)zb * sSb + (size_t)i * 2048;
  u16* prow = P + (size_t)zb * sPb + (size_t)i * 2048;
  const int Tend = ((i >> 7) + 1) << 7;  // multiple of 128
  const int nch = (Tend + 255) >> 8;

  f32x4 vb[8];
  float mx = -3e38f;
  for (int c = 0; c < nch; ++c) {
    const int j = c * 256 + l * 4;
    f32x4 v;
    if (j < Tend) v = *(const f32x4*)(row + j);
    else { v[0] = v[1] = v[2] = v[3] = -3e38f; }
    vb[c] = v;
    mx = fmaxf(mx, fmaxf(fmaxf(v[0], v[1]), fmaxf(v[2], v[3])));
  }
#pragma unroll
  for (int s = 32; s; s >>= 1) mx = fmaxf(mx, __shfl_xor(mx, s));

  float sum = 0.f;
  for (int c = 0; c < nch; ++c) {
    f32x4 v = vb[c];
#pragma unroll
    for (int j = 0; j < 4; ++j) {
      float e = expf(v[j] - mx);  // -1e30/-3e38 -> 0
      v[j] = e;
      sum += e;
    }
    vb[c] = v;
  }
#pragma unroll
  for (int s = 32; s; s >>= 1) sum += __shfl_xor(sum, s);
  const float inv = 1.f / sum;

  for (int c = 0; c < nch; ++c) {
    const int j = c * 256 + l * 4;
    if (j < Tend) {
      f32x4 v = vb[c];
      u16x4 o;
#pragma unroll
      for (int q = 0; q < 4; ++q) o[q] = f2h(v[q] * inv);
      *(u16x4*)(prow + j) = o;
    }
  }
}

// ---------------- orchestration ----------------
extern "C" void kernel_launch(void* const* d_in, const int* in_sizes, int n_in,
                              void* d_out, int out_size, void* d_ws, size_t ws_size,
                              hipStream_t stream) {
  const float* x  = (const float*)d_in[0];
  const float* Wq = (const float*)d_in[1];
  const float* Wk = (const float*)d_in[2];
  const float* Wv = (const float*)d_in[3];
  float* out = (float*)d_out;

  const int S = 2048, D = 768;
  const size_t ND = (size_t)8 * S * D;        // 12.58M
  const size_t NW = (size_t)D * D;            // 589824

  char* ws = (char*)d_ws;
  size_t off = 0;
  auto alloc = [&](size_t bytes) { size_t o = off; off = (off + bytes + 255) & ~(size_t)255; return o; };

  u16* xf   = (u16*)(ws + alloc(ND * 2));
  u16* qf   = (u16*)(ws + alloc(ND * 2));
  u16* vtf  = (u16*)(ws + alloc(ND * 2));
  u16* wq16 = (u16*)(ws + alloc(NW * 2));
  u16* wk16 = (u16*)(ws + alloc(NW * 2));
  u16* wvt16= (u16*)(ws + alloc(NW * 2));
  u16* mt16 = (u16*)(ws + alloc(NW * 2));
  const size_t fixed = off;

  const size_t perBatch = (size_t)S * S * 4 + (size_t)S * S * 2 + 512;  // scores f32 + P fp16
  int g = 0;
  for (int cand = 8; cand >= 1; cand >>= 1)
    if (fixed + (size_t)cand * perBatch <= ws_size) { g = cand; break; }
  if (!g) return;

  float* sc = (float*)(ws + alloc((size_t)g * S * S * 4));
  u16*   P  = (u16*)(ws + alloc((size_t)g * S * S * 2));

  // fused prep: fp16 casts + Wv transpose
  prep_kernel<<<15744, 256, 0, stream>>>(x, Wq, Wk, Wv, xf, wq16, wk16, wvt16);

  // Mt[e][d] = sum_h Wk[e][h] * Wq[d][h]   (= (Wq Wk^T)^T), fp16 out, BN=64
  gemm_k<2, 0, 0, 64, 2><<<72, 256, 0, stream>>>(
      wk16, 0, wq16, 0, mt16, 0, 768, 768, 768, 768, 12, 6);

  // fused q' + vt: 768 all-resident blocks x 2 jobs, 3-deep pipeline
  proj_kernel<<<768, 256, 0, stream>>>(xf, mt16, wvt16, qf, vtf);

  for (int b0 = 0; b0 < 8; b0 += g) {
    // scores[b][i][j] = q'[b,i] . x[b,j]  (causal tiles only, mask to -1e30)
    gemm_k<0, 1, 0, 128, 2><<<16 * 16 * g, 256, 0, stream>>>(
        qf + (size_t)b0 * S * D, (long)S * D,
        xf + (size_t)b0 * S * D, (long)S * D,
        sc, (long)S * S, 768, 768, 768, 2048, 16, 16);

    softmax_kernel<<<g * 512, 256, 0, stream>>>(sc, P, (long)S * S, (long)S * S);

    // out[b][i][h] = sum_{j<Tend} P[b][i][j] * vt[h][b*2048+j]  (3-deep, all-resident)
    gemm_k<0, 0, 1, 128, 3><<<6 * 16 * g, 256, 0, stream>>>(
        P, (long)S * S,
        vtf + (size_t)b0 * S, (long)S,
        out + (size_t)b0 * S * D, (long)S * D,
        2048, 2048, 16384, 768, 6, 16);
  }
}